// Round 1
// baseline (1600.405 us; speedup 1.0000x reference)
//
#include <hip/hip_runtime.h>
#include <math.h>

#define N_NODES 500000
#define G_SEG   25000
#define H_DIM   256

__device__ __forceinline__ float leaky(float x){ return x > 0.f ? x : 0.01f * x; }

// order-preserving encode for float atomicMax on unsigned
__device__ __forceinline__ unsigned enc_f(float f){
  unsigned u = __float_as_uint(f);
  return (u & 0x80000000u) ? ~u : (u | 0x80000000u);
}
__device__ __forceinline__ float dec_f(unsigned u){
  return __uint_as_float((u & 0x80000000u) ? (u ^ 0x80000000u) : ~u);
}

// K1: s = leaky(super_node); sws[g] = dot(s[g], w_align[H:2H])
__global__ __launch_bounds__(256) void k1_prep_super(
    const float* __restrict__ sn, const float* __restrict__ w_align,
    float* __restrict__ s_buf, float* __restrict__ sws)
{
  int g = blockIdx.x, t = threadIdx.x;
  float v = sn[g * H_DIM + t];
  float sv = leaky(v);
  s_buf[g * H_DIM + t] = sv;
  float p = sv * w_align[H_DIM + t];
  #pragma unroll
  for (int d = 1; d < 64; d <<= 1) p += __shfl_xor(p, d);
  __shared__ float red[4];
  int wid = t >> 6, lane = t & 63;
  if (lane == 0) red[wid] = p;
  __syncthreads();
  if (t == 0) sws[g] = red[0] + red[1] + red[2] + red[3];
}

// K2: score[i] = leaky(node[i]·wn + sws[seg[i]] + b0); atomicMax segment max.
// one wave per row: 64 lanes x float4 = 256 floats
__global__ __launch_bounds__(256) void k2_score(
    const float* __restrict__ node, const int* __restrict__ seg,
    const float* __restrict__ w_align, const float* __restrict__ b_align,
    const float* __restrict__ sws, float* __restrict__ score,
    unsigned* __restrict__ m_enc)
{
  int wib  = threadIdx.x >> 6;
  int lane = threadIdx.x & 63;
  int row  = blockIdx.x * 4 + wib;
  if (row >= N_NODES) return;
  const float4* n4 = (const float4*)node + row * (H_DIM / 4);
  const float4* w4 = (const float4*)w_align;
  float4 a = n4[lane];
  float4 b = w4[lane];
  float d = a.x * b.x + a.y * b.y + a.z * b.z + a.w * b.w;
  #pragma unroll
  for (int m = 1; m < 64; m <<= 1) d += __shfl_xor(d, m);
  if (lane == 0) {
    int sg = seg[row];
    float sc = leaky(d + sws[sg] + b_align[0]);
    score[row] = sc;
    atomicMax(&m_enc[sg], enc_f(sc));
  }
}

// K3: w = exp(score - m[seg]); store to attn_out; segmented-scan + run-leader atomicAdd denom
__global__ __launch_bounds__(256) void k3_wexp(
    const float* __restrict__ score, const int* __restrict__ seg,
    const unsigned* __restrict__ m_enc, float* __restrict__ attn_out,
    float* __restrict__ denom)
{
  int i = blockIdx.x * 256 + threadIdx.x;
  int lane = threadIdx.x & 63;
  float w = 0.f; int sg = -1;
  if (i < N_NODES) {
    sg = seg[i];
    w = expf(score[i] - dec_f(m_enc[sg]));
    attn_out[i] = w;
  }
  float v = w;
  #pragma unroll
  for (int d = 1; d < 64; d <<= 1) {
    float vv = __shfl_up(v, d);
    int   ss = __shfl_up(sg, d);
    if (lane >= d && ss == sg) v += vv;
  }
  int nxt = __shfl_down(sg, 1);
  bool last = (lane == 63) || (nxt != sg);
  if (last && sg >= 0) atomicAdd(&denom[sg], v);
}

// K4: attn /= denom[seg]
__global__ __launch_bounds__(256) void k4_norm(
    const int* __restrict__ seg, const float* __restrict__ denom,
    float* __restrict__ attn_out)
{
  int i = blockIdx.x * 256 + threadIdx.x;
  if (i < N_NODES) attn_out[i] /= denom[seg[i]];
}

// K5: hidden = node @ w_attend + b_attend; ctx[seg] += attn * hidden (fused, run-flush atomics)
// block: 256 thr, 64 rows x 256 cols tile, 8x8 per-thread register tile
__global__ __launch_bounds__(256) void k5_hidden_ctx(
    const float* __restrict__ node, const int* __restrict__ seg,
    const float* __restrict__ w_att, const float* __restrict__ b_att,
    const float* __restrict__ attn, float* __restrict__ ctx)
{
  __shared__ __align__(16) float nodeT[32][68];   // [k][r], pad 68
  __shared__ __align__(16) float wtile[32][256];  // [k][c]
  __shared__ float attn_s[64];
  __shared__ int   seg_s[64];

  int tid  = threadIdx.x;
  int row0 = blockIdx.x * 64;
  if (tid < 64) {
    int r = row0 + tid;
    attn_s[tid] = (r < N_NODES) ? attn[r] : 0.f;
    seg_s[tid]  = (r < N_NODES) ? seg[r]  : -1;
  }

  float acc[8][8];
  #pragma unroll
  for (int i = 0; i < 8; i++)
    #pragma unroll
    for (int j = 0; j < 8; j++) acc[i][j] = 0.f;

  int tr = tid >> 5;   // 0..7
  int tc = tid & 31;   // 0..31

  for (int k0 = 0; k0 < H_DIM; k0 += 32) {
    __syncthreads();
    // stage node^T: rows row0..row0+63, k-chunk k0..k0+31
    {
      int kq   = tid & 7;      // which float4 within the 32-k chunk
      int rloc = tid >> 3;     // 0..31
      #pragma unroll
      for (int q = 0; q < 2; q++) {
        int r = rloc + q * 32;
        int grow = row0 + r;
        float4 nv = make_float4(0.f, 0.f, 0.f, 0.f);
        if (grow < N_NODES)
          nv = ((const float4*)node)[grow * (H_DIM / 4) + (k0 >> 2) + kq];
        nodeT[kq * 4 + 0][r] = nv.x;
        nodeT[kq * 4 + 1][r] = nv.y;
        nodeT[kq * 4 + 2][r] = nv.z;
        nodeT[kq * 4 + 3][r] = nv.w;
      }
    }
    // stage w tile: w_att[k0..k0+31][0..255]
    {
      #pragma unroll
      for (int q = 0; q < 8; q++) {
        int vid = q * 256 + tid;  // float4 id 0..2047
        int kk  = vid >> 6;
        int c4  = vid & 63;
        ((float4*)&wtile[kk][0])[c4] =
            ((const float4*)w_att)[(k0 + kk) * (H_DIM / 4) + c4];
      }
    }
    __syncthreads();

    #pragma unroll 4
    for (int k = 0; k < 32; k++) {
      float4 a0 = *(const float4*)&nodeT[k][tr * 8];
      float4 a1 = *(const float4*)&nodeT[k][tr * 8 + 4];
      float4 b0 = *(const float4*)&wtile[k][tc * 8];
      float4 b1 = *(const float4*)&wtile[k][tc * 8 + 4];
      float av[8] = {a0.x, a0.y, a0.z, a0.w, a1.x, a1.y, a1.z, a1.w};
      float bv[8] = {b0.x, b0.y, b0.z, b0.w, b1.x, b1.y, b1.z, b1.w};
      #pragma unroll
      for (int i = 0; i < 8; i++)
        #pragma unroll
        for (int j = 0; j < 8; j++)
          acc[i][j] = fmaf(av[i], bv[j], acc[i][j]);
    }
  }

  // epilogue: bias, attn-weight, run-accumulate by segment, flush via atomics
  float bat[8];
  {
    float4 b0 = ((const float4*)b_att)[tc * 2];
    float4 b1 = ((const float4*)b_att)[tc * 2 + 1];
    bat[0] = b0.x; bat[1] = b0.y; bat[2] = b0.z; bat[3] = b0.w;
    bat[4] = b1.x; bat[5] = b1.y; bat[6] = b1.z; bat[7] = b1.w;
  }
  float run[8];
  #pragma unroll
  for (int j = 0; j < 8; j++) run[j] = 0.f;
  int cur = -2;  // sentinel distinct from any sg and from -1
  #pragma unroll
  for (int i = 0; i < 8; i++) {
    int rl = tr * 8 + i;
    int sg = seg_s[rl];
    float av = attn_s[rl];
    float c0 = av * (acc[i][0] + bat[0]);
    float c1 = av * (acc[i][1] + bat[1]);
    float c2 = av * (acc[i][2] + bat[2]);
    float c3 = av * (acc[i][3] + bat[3]);
    float c4 = av * (acc[i][4] + bat[4]);
    float c5 = av * (acc[i][5] + bat[5]);
    float c6 = av * (acc[i][6] + bat[6]);
    float c7 = av * (acc[i][7] + bat[7]);
    if (sg != cur) {
      if (cur >= 0) {
        float* cp = &ctx[cur * H_DIM + tc * 8];
        atomicAdd(cp + 0, run[0]); atomicAdd(cp + 1, run[1]);
        atomicAdd(cp + 2, run[2]); atomicAdd(cp + 3, run[3]);
        atomicAdd(cp + 4, run[4]); atomicAdd(cp + 5, run[5]);
        atomicAdd(cp + 6, run[6]); atomicAdd(cp + 7, run[7]);
      }
      cur = sg;
      run[0] = c0; run[1] = c1; run[2] = c2; run[3] = c3;
      run[4] = c4; run[5] = c5; run[6] = c6; run[7] = c7;
    } else {
      run[0] += c0; run[1] += c1; run[2] += c2; run[3] += c3;
      run[4] += c4; run[5] += c5; run[6] += c6; run[7] += c7;
    }
  }
  if (cur >= 0) {
    float* cp = &ctx[cur * H_DIM + tc * 8];
    atomicAdd(cp + 0, run[0]); atomicAdd(cp + 1, run[1]);
    atomicAdd(cp + 2, run[2]); atomicAdd(cp + 3, run[3]);
    atomicAdd(cp + 4, run[4]); atomicAdd(cp + 5, run[5]);
    atomicAdd(cp + 6, run[6]); atomicAdd(cp + 7, run[7]);
  }
}

// K6: gi = elu(ctx) @ w_ih + b_ih ; gh = s @ w_hh + b_hh ; GRU gates ; relu out
// block: 256 thr (one column each), 16 segment-rows per block
__global__ __launch_bounds__(256) void k6_gates(
    const float* __restrict__ ctxbuf, const float* __restrict__ s_buf,
    const float* __restrict__ w_ih, const float* __restrict__ w_hh,
    const float* __restrict__ b_ih, const float* __restrict__ b_hh,
    float* __restrict__ out0)
{
  __shared__ __align__(16) float ctx_s[16][H_DIM];
  __shared__ __align__(16) float ss_s[16][H_DIM];
  int tid = threadIdx.x;
  int g0 = blockIdx.x * 16;
  #pragma unroll
  for (int j = 0; j < 16; j++) {
    int g = g0 + j;
    float cv = 0.f, sv = 0.f;
    if (g < G_SEG) {
      cv = ctxbuf[g * H_DIM + tid];
      sv = s_buf[g * H_DIM + tid];
    }
    ctx_s[j][tid] = cv > 0.f ? cv : (expf(cv) - 1.f);  // elu
    ss_s[j][tid]  = sv;
  }
  __syncthreads();

  int c = tid;
  float air[16], aiz[16], ain[16], ahr[16], ahz[16], ahn[16];
  #pragma unroll
  for (int j = 0; j < 16; j++) {
    air[j] = 0.f; aiz[j] = 0.f; ain[j] = 0.f;
    ahr[j] = 0.f; ahz[j] = 0.f; ahn[j] = 0.f;
  }

  for (int k = 0; k < H_DIM; k += 4) {
    float wir[4], wiz[4], win[4], whr[4], whz[4], whn[4];
    #pragma unroll
    for (int kk = 0; kk < 4; kk++) {
      const float* wi = w_ih + (size_t)(k + kk) * 768;
      const float* wh = w_hh + (size_t)(k + kk) * 768;
      wir[kk] = wi[c];       wiz[kk] = wi[256 + c]; win[kk] = wi[512 + c];
      whr[kk] = wh[c];       whz[kk] = wh[256 + c]; whn[kk] = wh[512 + c];
    }
    #pragma unroll
    for (int j = 0; j < 16; j++) {
      float4 cv = *(const float4*)&ctx_s[j][k];
      float4 sv = *(const float4*)&ss_s[j][k];
      air[j] = fmaf(cv.x, wir[0], fmaf(cv.y, wir[1], fmaf(cv.z, wir[2], fmaf(cv.w, wir[3], air[j]))));
      aiz[j] = fmaf(cv.x, wiz[0], fmaf(cv.y, wiz[1], fmaf(cv.z, wiz[2], fmaf(cv.w, wiz[3], aiz[j]))));
      ain[j] = fmaf(cv.x, win[0], fmaf(cv.y, win[1], fmaf(cv.z, win[2], fmaf(cv.w, win[3], ain[j]))));
      ahr[j] = fmaf(sv.x, whr[0], fmaf(sv.y, whr[1], fmaf(sv.z, whr[2], fmaf(sv.w, whr[3], ahr[j]))));
      ahz[j] = fmaf(sv.x, whz[0], fmaf(sv.y, whz[1], fmaf(sv.z, whz[2], fmaf(sv.w, whz[3], ahz[j]))));
      ahn[j] = fmaf(sv.x, whn[0], fmaf(sv.y, whn[1], fmaf(sv.z, whn[2], fmaf(sv.w, whn[3], ahn[j]))));
    }
  }

  #pragma unroll
  for (int j = 0; j < 16; j++) {
    int g = g0 + j;
    if (g < G_SEG) {
      float ir  = air[j] + b_ih[c];
      float iz  = aiz[j] + b_ih[256 + c];
      float inn = ain[j] + b_ih[512 + c];
      float hr  = ahr[j] + b_hh[c];
      float hz  = ahz[j] + b_hh[256 + c];
      float hn  = ahn[j] + b_hh[512 + c];
      float r = 1.f / (1.f + expf(-(ir + hr)));
      float z = 1.f / (1.f + expf(-(iz + hz)));
      float n = tanhf(inn + r * hn);
      float sv = ss_s[j][c];
      float nh = (1.f - z) * n + z * sv;
      out0[g * H_DIM + c] = nh > 0.f ? nh : 0.f;
    }
  }
}

extern "C" void kernel_launch(void* const* d_in, const int* in_sizes, int n_in,
                              void* d_out, int out_size, void* d_ws, size_t ws_size,
                              hipStream_t stream)
{
  (void)in_sizes; (void)n_in; (void)out_size; (void)ws_size;
  const float* node       = (const float*)d_in[0];
  const float* super_node = (const float*)d_in[1];
  const int*   seg        = (const int*)d_in[2];
  const float* w_align    = (const float*)d_in[3];
  const float* b_align    = (const float*)d_in[4];
  const float* w_att      = (const float*)d_in[5];
  const float* b_att      = (const float*)d_in[6];
  const float* w_ih       = (const float*)d_in[7];
  const float* w_hh       = (const float*)d_in[8];
  const float* b_ih       = (const float*)d_in[9];
  const float* b_hh       = (const float*)d_in[10];

  float* out0     = (float*)d_out;                               // G*H
  float* attn_out = (float*)d_out + (size_t)G_SEG * H_DIM;       // N

  float* ws     = (float*)d_ws;
  float* s_buf  = ws;                    //  6,400,000 f32
  float* score  = ws + 6400000;          //    500,000
  float* sws    = ws + 6900000;          //     25,000
  float* ctx    = ws + 6925000;          //  6,400,000
  unsigned* m_enc = (unsigned*)(ws + 13325000);  // 25,000
  float* denom  = ws + 13350000;         //     25,000  (end: 13,375,000 f32 = 53.5 MB)

  // zero ctx + m_enc + denom (contiguous region)
  hipMemsetAsync(ctx, 0, (size_t)(6400000 + 25000 + 25000) * sizeof(float), stream);

  k1_prep_super<<<G_SEG, 256, 0, stream>>>(super_node, w_align, s_buf, sws);
  k2_score<<<(N_NODES + 3) / 4, 256, 0, stream>>>(node, seg, w_align, b_align, sws, score, m_enc);
  k3_wexp<<<(N_NODES + 255) / 256, 256, 0, stream>>>(score, seg, m_enc, attn_out, denom);
  k4_norm<<<(N_NODES + 255) / 256, 256, 0, stream>>>(seg, denom, attn_out);
  k5_hidden_ctx<<<(N_NODES + 63) / 64, 256, 0, stream>>>(node, seg, w_att, b_att, attn_out, ctx);
  k6_gates<<<(G_SEG + 15) / 16, 256, 0, stream>>>(ctx, s_buf, w_ih, w_hh, b_ih, b_hh, out0);
}

// Round 2
// 921.362 us; speedup vs baseline: 1.7370x; 1.7370x over previous
//
#include <hip/hip_runtime.h>
#include <math.h>

#define N_NODES 500000
#define G_SEG   25000
#define H_DIM   256

typedef __attribute__((ext_vector_type(4))) float f32x4;
typedef __attribute__((ext_vector_type(8))) short bf16x8;

__device__ __forceinline__ float leaky(float x){ return x > 0.f ? x : 0.01f * x; }

// round-to-nearest-even f32 -> bf16
__device__ __forceinline__ ushort f2bf(float f){
  unsigned u = __float_as_uint(f);
  u += 0x7FFFu + ((u >> 16) & 1u);
  return (ushort)(u >> 16);
}

// order-preserving encode for float atomicMax on unsigned
__device__ __forceinline__ unsigned enc_f(float f){
  unsigned u = __float_as_uint(f);
  return (u & 0x80000000u) ? ~u : (u | 0x80000000u);
}
__device__ __forceinline__ float dec_f(unsigned u){
  return __uint_as_float((u & 0x80000000u) ? (u ^ 0x80000000u) : ~u);
}

// K0: pre-pack w_attend (256x256 f32) into bf16 fragment layout:
// value W[kk][n] -> Bp[((kk>>3)*256 + n)*8 + (kk&7)]
// so a lane's 8-k fragment (chunk c, col n) is 16B contiguous at (c*256+n)*16.
__global__ __launch_bounds__(256) void k0_prep_w(
    const float* __restrict__ w_att, ushort* __restrict__ Bp)
{
  int kk = blockIdx.x, n = threadIdx.x;
  Bp[(((kk >> 3) << 8) + n) * 8 + (kk & 7)] = f2bf(w_att[kk * H_DIM + n]);
}

// K1: s = leaky(super_node); sws[g] = dot(s[g], w_align[H:2H])
__global__ __launch_bounds__(256) void k1_prep_super(
    const float* __restrict__ sn, const float* __restrict__ w_align,
    float* __restrict__ s_buf, float* __restrict__ sws)
{
  int g = blockIdx.x, t = threadIdx.x;
  float v = sn[g * H_DIM + t];
  float sv = leaky(v);
  s_buf[g * H_DIM + t] = sv;
  float p = sv * w_align[H_DIM + t];
  #pragma unroll
  for (int d = 1; d < 64; d <<= 1) p += __shfl_xor(p, d);
  __shared__ float red[4];
  int wid = t >> 6, lane = t & 63;
  if (lane == 0) red[wid] = p;
  __syncthreads();
  if (t == 0) sws[g] = red[0] + red[1] + red[2] + red[3];
}

// K2: score[i] = leaky(node[i]·wn + sws[seg[i]] + b0); atomicMax segment max.
__global__ __launch_bounds__(256) void k2_score(
    const float* __restrict__ node, const int* __restrict__ seg,
    const float* __restrict__ w_align, const float* __restrict__ b_align,
    const float* __restrict__ sws, float* __restrict__ score,
    unsigned* __restrict__ m_enc)
{
  int wib  = threadIdx.x >> 6;
  int lane = threadIdx.x & 63;
  int row  = blockIdx.x * 4 + wib;
  if (row >= N_NODES) return;
  const float4* n4 = (const float4*)node + row * (H_DIM / 4);
  const float4* w4 = (const float4*)w_align;
  float4 a = n4[lane];
  float4 b = w4[lane];
  float d = a.x * b.x + a.y * b.y + a.z * b.z + a.w * b.w;
  #pragma unroll
  for (int m = 1; m < 64; m <<= 1) d += __shfl_xor(d, m);
  if (lane == 0) {
    int sg = seg[row];
    float sc = leaky(d + sws[sg] + b_align[0]);
    score[row] = sc;
    atomicMax(&m_enc[sg], enc_f(sc));
  }
}

// K3: w = exp(score - m[seg]); segmented-scan + run-leader atomicAdd denom
__global__ __launch_bounds__(256) void k3_wexp(
    const float* __restrict__ score, const int* __restrict__ seg,
    const unsigned* __restrict__ m_enc, float* __restrict__ attn_out,
    float* __restrict__ denom)
{
  int i = blockIdx.x * 256 + threadIdx.x;
  int lane = threadIdx.x & 63;
  float w = 0.f; int sg = -1;
  if (i < N_NODES) {
    sg = seg[i];
    w = expf(score[i] - dec_f(m_enc[sg]));
    attn_out[i] = w;
  }
  float v = w;
  #pragma unroll
  for (int d = 1; d < 64; d <<= 1) {
    float vv = __shfl_up(v, d);
    int   ss = __shfl_up(sg, d);
    if (lane >= d && ss == sg) v += vv;
  }
  int nxt = __shfl_down(sg, 1);
  bool last = (lane == 63) || (nxt != sg);
  if (last && sg >= 0) atomicAdd(&denom[sg], v);
}

// K4: attn /= denom[seg]
__global__ __launch_bounds__(256) void k4_norm(
    const int* __restrict__ seg, const float* __restrict__ denom,
    float* __restrict__ attn_out)
{
  int i = blockIdx.x * 256 + threadIdx.x;
  if (i < N_NODES) attn_out[i] /= denom[seg[i]];
}

// K5 (MFMA): hidden = node @ w_attend + b_attend; ctx[seg] += attn * hidden.
// 256 thr = 4 waves. Tile: 128 rows x 256 cols, K=256 staged in LDS as bf16
// with XOR 16B-slot swizzle. Wave w computes cols [w*64, w*64+64).
// Per wave: 8 m-frags x 4 n-frags of 16x16, mfma_f32_16x16x32_bf16.
// Epilogue: per-lane segment run-accumulate -> LDS cpart (aliased onto dead
// A-tile) -> one global atomic per (segment,col) per block.
__global__ __launch_bounds__(256, 2) void k5_hidden_ctx(
    const float* __restrict__ node, const int* __restrict__ seg,
    const ushort* __restrict__ Bp, const float* __restrict__ b_att,
    const float* __restrict__ attn, float* __restrict__ ctx)
{
  __shared__ __align__(16) ushort A_lds[128 * 256];  // 64KB
  __shared__ float attn_s[128];
  __shared__ int   seg_s[128];

  const int tid  = threadIdx.x;
  const int row0 = blockIdx.x * 128;

  // stage A: node rows row0..row0+127, f32 -> bf16, 16B slots swizzled by row&7
  #pragma unroll
  for (int i = 0; i < 16; i++) {
    int v = tid + i * 256;     // slot id 0..4095
    int r = v >> 5;            // local row
    int s = v & 31;            // 16B slot within row (8 bf16 = 8 k)
    int grow = row0 + r;
    f32x4 x0 = {0.f, 0.f, 0.f, 0.f}, x1 = {0.f, 0.f, 0.f, 0.f};
    if (grow < N_NODES) {
      const f32x4* p = (const f32x4*)(node + (size_t)grow * H_DIM) + s * 2;
      x0 = p[0]; x1 = p[1];
    }
    bf16x8 t;
    t[0] = (short)f2bf(x0[0]); t[1] = (short)f2bf(x0[1]);
    t[2] = (short)f2bf(x0[2]); t[3] = (short)f2bf(x0[3]);
    t[4] = (short)f2bf(x1[0]); t[5] = (short)f2bf(x1[1]);
    t[6] = (short)f2bf(x1[2]); t[7] = (short)f2bf(x1[3]);
    *(bf16x8*)&A_lds[r * 256 + ((s ^ (r & 7)) * 8)] = t;
  }
  if (tid < 128) {
    int grow = row0 + tid;
    attn_s[tid] = (grow < N_NODES) ? attn[grow] : 0.f;
    seg_s[tid]  = (grow < N_NODES) ? seg[grow] : (G_SEG - 1);
  }
  __syncthreads();

  const int wv  = tid >> 6;
  const int l   = tid & 63;
  const int l15 = l & 15, lq = l >> 4, l7 = l & 7;
  const int colbase = wv * 64 + l15;

  f32x4 acc[8][4];
  #pragma unroll
  for (int mf = 0; mf < 8; mf++)
    #pragma unroll
    for (int nf = 0; nf < 4; nf++)
      acc[mf][nf] = (f32x4){0.f, 0.f, 0.f, 0.f};

  for (int ks = 0; ks < 8; ks++) {
    int c = ks * 4 + lq;  // k-chunk 0..31 (8 k each)
    bf16x8 b[4];
    #pragma unroll
    for (int nf = 0; nf < 4; nf++)
      b[nf] = *(const bf16x8*)&Bp[(((c << 8) + colbase + nf * 16)) * 8];
    bf16x8 a[8];
    #pragma unroll
    for (int mf = 0; mf < 8; mf++)
      a[mf] = *(const bf16x8*)&A_lds[(mf * 16 + l15) * 256 + ((c ^ l7) * 8)];
    #pragma unroll
    for (int mf = 0; mf < 8; mf++)
      #pragma unroll
      for (int nf = 0; nf < 4; nf++)
        acc[mf][nf] = __builtin_amdgcn_mfma_f32_16x16x32_bf16(
            a[mf], b[nf], acc[mf][nf], 0, 0, 0);
  }

  float bias[4];
  #pragma unroll
  for (int nf = 0; nf < 4; nf++) bias[nf] = b_att[colbase + nf * 16];

  const int seg_first = seg_s[0];
  const int nseg = seg_s[127] - seg_first + 1;

  __syncthreads();  // all A_lds reads done before aliasing as cpart

  if (nseg <= 32) {
    float* cpart = (float*)A_lds;  // 32 x 256 f32 = 32KB (aliases A tile)
    #pragma unroll
    for (int i = 0; i < 32; i++) cpart[tid + i * 256] = 0.f;
    __syncthreads();

    float run[4] = {0.f, 0.f, 0.f, 0.f};
    int cur = -1;
    #pragma unroll
    for (int mf = 0; mf < 8; mf++) {
      #pragma unroll
      for (int r = 0; r < 4; r++) {
        int row = mf * 16 + lq * 4 + r;   // D row for this lane/reg
        int sg = seg_s[row];
        float av = attn_s[row];
        if (sg != cur) {
          if (cur >= 0) {
            int li = cur - seg_first;
            #pragma unroll
            for (int nf = 0; nf < 4; nf++)
              atomicAdd(&cpart[li * 256 + colbase + nf * 16], run[nf]);
          }
          cur = sg;
          #pragma unroll
          for (int nf = 0; nf < 4; nf++)
            run[nf] = av * (acc[mf][nf][r] + bias[nf]);
        } else {
          #pragma unroll
          for (int nf = 0; nf < 4; nf++)
            run[nf] += av * (acc[mf][nf][r] + bias[nf]);
        }
      }
    }
    if (cur >= 0) {
      int li = cur - seg_first;
      #pragma unroll
      for (int nf = 0; nf < 4; nf++)
        atomicAdd(&cpart[li * 256 + colbase + nf * 16], run[nf]);
    }
    __syncthreads();
    for (int s2 = 0; s2 < nseg; s2++) {
      float v = cpart[s2 * 256 + tid];
      atomicAdd(&ctx[(size_t)(seg_first + s2) * H_DIM + tid], v);
    }
  } else {
    // rare fallback: direct global atomics
    float run[4] = {0.f, 0.f, 0.f, 0.f};
    int cur = -1;
    #pragma unroll
    for (int mf = 0; mf < 8; mf++) {
      #pragma unroll
      for (int r = 0; r < 4; r++) {
        int row = mf * 16 + lq * 4 + r;
        int sg = seg_s[row];
        float av = attn_s[row];
        if (sg != cur) {
          if (cur >= 0) {
            #pragma unroll
            for (int nf = 0; nf < 4; nf++)
              atomicAdd(&ctx[(size_t)cur * H_DIM + colbase + nf * 16], run[nf]);
          }
          cur = sg;
          #pragma unroll
          for (int nf = 0; nf < 4; nf++)
            run[nf] = av * (acc[mf][nf][r] + bias[nf]);
        } else {
          #pragma unroll
          for (int nf = 0; nf < 4; nf++)
            run[nf] += av * (acc[mf][nf][r] + bias[nf]);
        }
      }
    }
    if (cur >= 0) {
      #pragma unroll
      for (int nf = 0; nf < 4; nf++)
        atomicAdd(&ctx[(size_t)cur * H_DIM + colbase + nf * 16], run[nf]);
    }
  }
}

// K6: gi = elu(ctx) @ w_ih + b_ih ; gh = s @ w_hh + b_hh ; GRU gates ; relu out
__global__ __launch_bounds__(256) void k6_gates(
    const float* __restrict__ ctxbuf, const float* __restrict__ s_buf,
    const float* __restrict__ w_ih, const float* __restrict__ w_hh,
    const float* __restrict__ b_ih, const float* __restrict__ b_hh,
    float* __restrict__ out0)
{
  __shared__ __align__(16) float ctx_s[16][H_DIM];
  __shared__ __align__(16) float ss_s[16][H_DIM];
  int tid = threadIdx.x;
  int g0 = blockIdx.x * 16;
  #pragma unroll
  for (int j = 0; j < 16; j++) {
    int g = g0 + j;
    float cv = 0.f, sv = 0.f;
    if (g < G_SEG) {
      cv = ctxbuf[g * H_DIM + tid];
      sv = s_buf[g * H_DIM + tid];
    }
    ctx_s[j][tid] = cv > 0.f ? cv : (expf(cv) - 1.f);  // elu
    ss_s[j][tid]  = sv;
  }
  __syncthreads();

  int c = tid;
  float air[16], aiz[16], ain[16], ahr[16], ahz[16], ahn[16];
  #pragma unroll
  for (int j = 0; j < 16; j++) {
    air[j] = 0.f; aiz[j] = 0.f; ain[j] = 0.f;
    ahr[j] = 0.f; ahz[j] = 0.f; ahn[j] = 0.f;
  }

  for (int k = 0; k < H_DIM; k += 4) {
    float wir[4], wiz[4], win[4], whr[4], whz[4], whn[4];
    #pragma unroll
    for (int kk = 0; kk < 4; kk++) {
      const float* wi = w_ih + (size_t)(k + kk) * 768;
      const float* wh = w_hh + (size_t)(k + kk) * 768;
      wir[kk] = wi[c];       wiz[kk] = wi[256 + c]; win[kk] = wi[512 + c];
      whr[kk] = wh[c];       whz[kk] = wh[256 + c]; whn[kk] = wh[512 + c];
    }
    #pragma unroll
    for (int j = 0; j < 16; j++) {
      float4 cv = *(const float4*)&ctx_s[j][k];
      float4 sv = *(const float4*)&ss_s[j][k];
      air[j] = fmaf(cv.x, wir[0], fmaf(cv.y, wir[1], fmaf(cv.z, wir[2], fmaf(cv.w, wir[3], air[j]))));
      aiz[j] = fmaf(cv.x, wiz[0], fmaf(cv.y, wiz[1], fmaf(cv.z, wiz[2], fmaf(cv.w, wiz[3], aiz[j]))));
      ain[j] = fmaf(cv.x, win[0], fmaf(cv.y, win[1], fmaf(cv.z, win[2], fmaf(cv.w, win[3], ain[j]))));
      ahr[j] = fmaf(sv.x, whr[0], fmaf(sv.y, whr[1], fmaf(sv.z, whr[2], fmaf(sv.w, whr[3], ahr[j]))));
      ahz[j] = fmaf(sv.x, whz[0], fmaf(sv.y, whz[1], fmaf(sv.z, whz[2], fmaf(sv.w, whz[3], ahz[j]))));
      ahn[j] = fmaf(sv.x, whn[0], fmaf(sv.y, whn[1], fmaf(sv.z, whn[2], fmaf(sv.w, whn[3], ahn[j]))));
    }
  }

  #pragma unroll
  for (int j = 0; j < 16; j++) {
    int g = g0 + j;
    if (g < G_SEG) {
      float ir  = air[j] + b_ih[c];
      float iz  = aiz[j] + b_ih[256 + c];
      float inn = ain[j] + b_ih[512 + c];
      float hr  = ahr[j] + b_hh[c];
      float hz  = ahz[j] + b_hh[256 + c];
      float hn  = ahn[j] + b_hh[512 + c];
      float r = 1.f / (1.f + expf(-(ir + hr)));
      float z = 1.f / (1.f + expf(-(iz + hz)));
      float n = tanhf(inn + r * hn);
      float sv = ss_s[j][c];
      float nh = (1.f - z) * n + z * sv;
      out0[g * H_DIM + c] = nh > 0.f ? nh : 0.f;
    }
  }
}

extern "C" void kernel_launch(void* const* d_in, const int* in_sizes, int n_in,
                              void* d_out, int out_size, void* d_ws, size_t ws_size,
                              hipStream_t stream)
{
  (void)in_sizes; (void)n_in; (void)out_size; (void)ws_size;
  const float* node       = (const float*)d_in[0];
  const float* super_node = (const float*)d_in[1];
  const int*   seg        = (const int*)d_in[2];
  const float* w_align    = (const float*)d_in[3];
  const float* b_align    = (const float*)d_in[4];
  const float* w_att      = (const float*)d_in[5];
  const float* b_att      = (const float*)d_in[6];
  const float* w_ih       = (const float*)d_in[7];
  const float* w_hh       = (const float*)d_in[8];
  const float* b_ih       = (const float*)d_in[9];
  const float* b_hh       = (const float*)d_in[10];

  float* out0     = (float*)d_out;                               // G*H
  float* attn_out = (float*)d_out + (size_t)G_SEG * H_DIM;       // N

  float* ws     = (float*)d_ws;
  float* s_buf  = ws;                    //  6,400,000 f32
  float* score  = ws + 6400000;          //    500,000 (dead after k3; Bp aliases it)
  float* sws    = ws + 6900000;          //     25,000
  float* ctx    = ws + 6925000;          //  6,400,000
  unsigned* m_enc = (unsigned*)(ws + 13325000);  // 25,000
  float* denom  = ws + 13350000;         //     25,000
  ushort* Bp    = (ushort*)score;        //    65,536 ushort (aliases dead score)

  // zero ctx + m_enc + denom (contiguous region)
  hipMemsetAsync(ctx, 0, (size_t)(6400000 + 25000 + 25000) * sizeof(float), stream);

  k1_prep_super<<<G_SEG, 256, 0, stream>>>(super_node, w_align, s_buf, sws);
  k2_score<<<(N_NODES + 3) / 4, 256, 0, stream>>>(node, seg, w_align, b_align, sws, score, m_enc);
  k3_wexp<<<(N_NODES + 255) / 256, 256, 0, stream>>>(score, seg, m_enc, attn_out, denom);
  k4_norm<<<(N_NODES + 255) / 256, 256, 0, stream>>>(seg, denom, attn_out);
  k0_prep_w<<<H_DIM, H_DIM, 0, stream>>>(w_att, Bp);  // after k3: Bp aliases score
  k5_hidden_ctx<<<(N_NODES + 127) / 128, 256, 0, stream>>>(node, seg, Bp, b_att, attn_out, ctx);
  k6_gates<<<(G_SEG + 15) / 16, 256, 0, stream>>>(ctx, s_buf, w_ih, w_hh, b_ih, b_hh, out0);
}

// Round 3
// 585.549 us; speedup vs baseline: 2.7332x; 1.5735x over previous
//
#include <hip/hip_runtime.h>
#include <math.h>

#define N_NODES 500000
#define G_SEG   25000
#define H_DIM   256

typedef __attribute__((ext_vector_type(4))) float f32x4;
typedef __attribute__((ext_vector_type(8))) short bf16x8;

__device__ __forceinline__ float leaky(float x){ return x > 0.f ? x : 0.01f * x; }

// round-to-nearest-even f32 -> bf16
__device__ __forceinline__ ushort f2bf(float f){
  unsigned u = __float_as_uint(f);
  u += 0x7FFFu + ((u >> 16) & 1u);
  return (ushort)(u >> 16);
}

// order-preserving encode for float atomicMax on unsigned
__device__ __forceinline__ unsigned enc_f(float f){
  unsigned u = __float_as_uint(f);
  return (u & 0x80000000u) ? ~u : (u | 0x80000000u);
}
__device__ __forceinline__ float dec_f(unsigned u){
  return __uint_as_float((u & 0x80000000u) ? (u ^ 0x80000000u) : ~u);
}

// K0: pre-pack w_attend (256x256 f32) into bf16 fragment layout:
// W[kk][n] -> Bp[((kk>>3)*256 + n)*8 + (kk&7)]
__global__ __launch_bounds__(256) void k0_prep_w(
    const float* __restrict__ w_att, ushort* __restrict__ Bp)
{
  int kk = blockIdx.x, n = threadIdx.x;
  Bp[(((kk >> 3) << 8) + n) * 8 + (kk & 7)] = f2bf(w_att[kk * H_DIM + n]);
}

// K0b: pack GRU weights into Bp6[512 x 1024] bf16 fragment layout.
// Column space n = gate*256 + c:
//  gate0: kk<256 ? w_ih[kk][c]      : w_hh[kk-256][c]       -> ir+hr
//  gate1: kk<256 ? w_ih[kk][256+c]  : w_hh[kk-256][256+c]   -> iz+hz
//  gate2: kk<256 ? w_ih[kk][512+c]  : 0                     -> inn
//  gate3: kk<256 ? 0                : w_hh[kk-256][512+c]   -> hn
// layout: value(kk,n) -> Bp6[((kk>>3)*1024 + n)*8 + (kk&7)]
__global__ __launch_bounds__(256) void k0b_prep_w6(
    const float* __restrict__ w_ih, const float* __restrict__ w_hh,
    ushort* __restrict__ Bp6)
{
  int kk = blockIdx.x;   // 0..511
  int c  = threadIdx.x;  // 0..255
  #pragma unroll
  for (int gate = 0; gate < 4; gate++) {
    float v;
    if (gate == 0)      v = (kk < 256) ? w_ih[kk * 768 + c]        : w_hh[(kk - 256) * 768 + c];
    else if (gate == 1) v = (kk < 256) ? w_ih[kk * 768 + 256 + c]  : w_hh[(kk - 256) * 768 + 256 + c];
    else if (gate == 2) v = (kk < 256) ? w_ih[kk * 768 + 512 + c]  : 0.f;
    else                v = (kk < 256) ? 0.f                       : w_hh[(kk - 256) * 768 + 512 + c];
    int n = (gate << 8) + c;
    Bp6[(((kk >> 3) << 10) + n) * 8 + (kk & 7)] = f2bf(v);
  }
}

// K1: s = leaky(super_node); sws[g] = dot(s[g], w_align[H:2H])
__global__ __launch_bounds__(256) void k1_prep_super(
    const float* __restrict__ sn, const float* __restrict__ w_align,
    float* __restrict__ s_buf, float* __restrict__ sws)
{
  int g = blockIdx.x, t = threadIdx.x;
  float v = sn[g * H_DIM + t];
  float sv = leaky(v);
  s_buf[g * H_DIM + t] = sv;
  float p = sv * w_align[H_DIM + t];
  #pragma unroll
  for (int d = 1; d < 64; d <<= 1) p += __shfl_xor(p, d);
  __shared__ float red[4];
  int wid = t >> 6, lane = t & 63;
  if (lane == 0) red[wid] = p;
  __syncthreads();
  if (t == 0) sws[g] = red[0] + red[1] + red[2] + red[3];
}

// K2: score[i] = leaky(node[i]·wn + sws[seg[i]] + b0); atomicMax segment max.
__global__ __launch_bounds__(256) void k2_score(
    const float* __restrict__ node, const int* __restrict__ seg,
    const float* __restrict__ w_align, const float* __restrict__ b_align,
    const float* __restrict__ sws, float* __restrict__ score,
    unsigned* __restrict__ m_enc)
{
  int wib  = threadIdx.x >> 6;
  int lane = threadIdx.x & 63;
  int row  = blockIdx.x * 4 + wib;
  if (row >= N_NODES) return;
  const float4* n4 = (const float4*)node + row * (H_DIM / 4);
  const float4* w4 = (const float4*)w_align;
  float4 a = n4[lane];
  float4 b = w4[lane];
  float d = a.x * b.x + a.y * b.y + a.z * b.z + a.w * b.w;
  #pragma unroll
  for (int m = 1; m < 64; m <<= 1) d += __shfl_xor(d, m);
  if (lane == 0) {
    int sg = seg[row];
    float sc = leaky(d + sws[sg] + b_align[0]);
    score[row] = sc;
    atomicMax(&m_enc[sg], enc_f(sc));
  }
}

// K3: w = exp(score - m[seg]); segmented-scan + run-leader atomicAdd denom
__global__ __launch_bounds__(256) void k3_wexp(
    const float* __restrict__ score, const int* __restrict__ seg,
    const unsigned* __restrict__ m_enc, float* __restrict__ attn_out,
    float* __restrict__ denom)
{
  int i = blockIdx.x * 256 + threadIdx.x;
  int lane = threadIdx.x & 63;
  float w = 0.f; int sg = -1;
  if (i < N_NODES) {
    sg = seg[i];
    w = expf(score[i] - dec_f(m_enc[sg]));
    attn_out[i] = w;
  }
  float v = w;
  #pragma unroll
  for (int d = 1; d < 64; d <<= 1) {
    float vv = __shfl_up(v, d);
    int   ss = __shfl_up(sg, d);
    if (lane >= d && ss == sg) v += vv;
  }
  int nxt = __shfl_down(sg, 1);
  bool last = (lane == 63) || (nxt != sg);
  if (last && sg >= 0) atomicAdd(&denom[sg], v);
}

// K4: attn /= denom[seg]
__global__ __launch_bounds__(256) void k4_norm(
    const int* __restrict__ seg, const float* __restrict__ denom,
    float* __restrict__ attn_out)
{
  int i = blockIdx.x * 256 + threadIdx.x;
  if (i < N_NODES) attn_out[i] /= denom[seg[i]];
}

// K5 (MFMA): hidden = node @ w_attend + b_attend; ctx[seg] += attn * hidden.
__global__ __launch_bounds__(256, 2) void k5_hidden_ctx(
    const float* __restrict__ node, const int* __restrict__ seg,
    const ushort* __restrict__ Bp, const float* __restrict__ b_att,
    const float* __restrict__ attn, float* __restrict__ ctx)
{
  __shared__ __align__(16) ushort A_lds[128 * 256];  // 64KB
  __shared__ float attn_s[128];
  __shared__ int   seg_s[128];

  const int tid  = threadIdx.x;
  const int row0 = blockIdx.x * 128;

  #pragma unroll
  for (int i = 0; i < 16; i++) {
    int v = tid + i * 256;
    int r = v >> 5;
    int s = v & 31;
    int grow = row0 + r;
    f32x4 x0 = {0.f, 0.f, 0.f, 0.f}, x1 = {0.f, 0.f, 0.f, 0.f};
    if (grow < N_NODES) {
      const f32x4* p = (const f32x4*)(node + (size_t)grow * H_DIM) + s * 2;
      x0 = p[0]; x1 = p[1];
    }
    bf16x8 t;
    t[0] = (short)f2bf(x0[0]); t[1] = (short)f2bf(x0[1]);
    t[2] = (short)f2bf(x0[2]); t[3] = (short)f2bf(x0[3]);
    t[4] = (short)f2bf(x1[0]); t[5] = (short)f2bf(x1[1]);
    t[6] = (short)f2bf(x1[2]); t[7] = (short)f2bf(x1[3]);
    *(bf16x8*)&A_lds[r * 256 + ((s ^ (r & 7)) * 8)] = t;
  }
  if (tid < 128) {
    int grow = row0 + tid;
    attn_s[tid] = (grow < N_NODES) ? attn[grow] : 0.f;
    seg_s[tid]  = (grow < N_NODES) ? seg[grow] : (G_SEG - 1);
  }
  __syncthreads();

  const int wv  = tid >> 6;
  const int l   = tid & 63;
  const int l15 = l & 15, lq = l >> 4, l7 = l & 7;
  const int colbase = wv * 64 + l15;

  f32x4 acc[8][4];
  #pragma unroll
  for (int mf = 0; mf < 8; mf++)
    #pragma unroll
    for (int nf = 0; nf < 4; nf++)
      acc[mf][nf] = (f32x4){0.f, 0.f, 0.f, 0.f};

  for (int ks = 0; ks < 8; ks++) {
    int c = ks * 4 + lq;
    bf16x8 b[4];
    #pragma unroll
    for (int nf = 0; nf < 4; nf++)
      b[nf] = *(const bf16x8*)&Bp[(((c << 8) + colbase + nf * 16)) * 8];
    bf16x8 a[8];
    #pragma unroll
    for (int mf = 0; mf < 8; mf++)
      a[mf] = *(const bf16x8*)&A_lds[(mf * 16 + l15) * 256 + ((c ^ l7) * 8)];
    #pragma unroll
    for (int mf = 0; mf < 8; mf++)
      #pragma unroll
      for (int nf = 0; nf < 4; nf++)
        acc[mf][nf] = __builtin_amdgcn_mfma_f32_16x16x32_bf16(
            a[mf], b[nf], acc[mf][nf], 0, 0, 0);
  }

  float bias[4];
  #pragma unroll
  for (int nf = 0; nf < 4; nf++) bias[nf] = b_att[colbase + nf * 16];

  const int seg_first = seg_s[0];
  const int nseg = seg_s[127] - seg_first + 1;

  __syncthreads();

  if (nseg <= 32) {
    float* cpart = (float*)A_lds;
    #pragma unroll
    for (int i = 0; i < 32; i++) cpart[tid + i * 256] = 0.f;
    __syncthreads();

    float run[4] = {0.f, 0.f, 0.f, 0.f};
    int cur = -1;
    #pragma unroll
    for (int mf = 0; mf < 8; mf++) {
      #pragma unroll
      for (int r = 0; r < 4; r++) {
        int row = mf * 16 + lq * 4 + r;
        int sg = seg_s[row];
        float av = attn_s[row];
        if (sg != cur) {
          if (cur >= 0) {
            int li = cur - seg_first;
            #pragma unroll
            for (int nf = 0; nf < 4; nf++)
              atomicAdd(&cpart[li * 256 + colbase + nf * 16], run[nf]);
          }
          cur = sg;
          #pragma unroll
          for (int nf = 0; nf < 4; nf++)
            run[nf] = av * (acc[mf][nf][r] + bias[nf]);
        } else {
          #pragma unroll
          for (int nf = 0; nf < 4; nf++)
            run[nf] += av * (acc[mf][nf][r] + bias[nf]);
        }
      }
    }
    if (cur >= 0) {
      int li = cur - seg_first;
      #pragma unroll
      for (int nf = 0; nf < 4; nf++)
        atomicAdd(&cpart[li * 256 + colbase + nf * 16], run[nf]);
    }
    __syncthreads();
    for (int s2 = 0; s2 < nseg; s2++) {
      float v = cpart[s2 * 256 + tid];
      atomicAdd(&ctx[(size_t)(seg_first + s2) * H_DIM + tid], v);
    }
  } else {
    float run[4] = {0.f, 0.f, 0.f, 0.f};
    int cur = -1;
    #pragma unroll
    for (int mf = 0; mf < 8; mf++) {
      #pragma unroll
      for (int r = 0; r < 4; r++) {
        int row = mf * 16 + lq * 4 + r;
        int sg = seg_s[row];
        float av = attn_s[row];
        if (sg != cur) {
          if (cur >= 0) {
            #pragma unroll
            for (int nf = 0; nf < 4; nf++)
              atomicAdd(&ctx[(size_t)cur * H_DIM + colbase + nf * 16], run[nf]);
          }
          cur = sg;
          #pragma unroll
          for (int nf = 0; nf < 4; nf++)
            run[nf] = av * (acc[mf][nf][r] + bias[nf]);
        } else {
          #pragma unroll
          for (int nf = 0; nf < 4; nf++)
            run[nf] += av * (acc[mf][nf][r] + bias[nf]);
        }
      }
    }
    if (cur >= 0) {
      #pragma unroll
      for (int nf = 0; nf < 4; nf++)
        atomicAdd(&ctx[(size_t)cur * H_DIM + colbase + nf * 16], run[nf]);
    }
  }
}

// K6 (MFMA): GRU gates. A = [elu(ctx) | s] (G x 512) staged bf16 in LDS.
// B = Bp6 (512 x 1024, 4 gate col-blocks) read as fragments from L2.
// Block: 256 thr = 4 waves, 32 rows. Wave w computes gate-block w for a
// 64-col slice; cslice loop x4. Gate combine in LDS -> sigmoid/tanh -> out.
__global__ __launch_bounds__(256, 2) void k6_mfma(
    const float* __restrict__ ctxbuf, const float* __restrict__ s_buf,
    const ushort* __restrict__ Bp6,
    const float* __restrict__ b_ih, const float* __restrict__ b_hh,
    float* __restrict__ out0)
{
  __shared__ __align__(16) ushort A_lds[32 * 512];   // 32KB
  __shared__ __align__(16) float  gate_s[32 * 256];  // 32KB

  const int tid  = threadIdx.x;
  const int row0 = blockIdx.x * 32;

  // stage A: 32 rows x 64 slots (8 bf16 each); slot<32 -> elu(ctx), else s
  #pragma unroll
  for (int i = 0; i < 8; i++) {
    int v = tid + i * 256;
    int r = v >> 6;
    int s = v & 63;
    int g = row0 + r;
    f32x4 x0 = {0.f, 0.f, 0.f, 0.f}, x1 = {0.f, 0.f, 0.f, 0.f};
    if (g < G_SEG) {
      const f32x4* p = (s < 32)
          ? (const f32x4*)(ctxbuf + (size_t)g * H_DIM) + s * 2
          : (const f32x4*)(s_buf + (size_t)g * H_DIM) + (s - 32) * 2;
      x0 = p[0]; x1 = p[1];
      if (s < 32) {
        #pragma unroll
        for (int e = 0; e < 4; e++) {
          x0[e] = x0[e] > 0.f ? x0[e] : (expf(x0[e]) - 1.f);
          x1[e] = x1[e] > 0.f ? x1[e] : (expf(x1[e]) - 1.f);
        }
      }
    }
    bf16x8 t;
    t[0] = (short)f2bf(x0[0]); t[1] = (short)f2bf(x0[1]);
    t[2] = (short)f2bf(x0[2]); t[3] = (short)f2bf(x0[3]);
    t[4] = (short)f2bf(x1[0]); t[5] = (short)f2bf(x1[1]);
    t[6] = (short)f2bf(x1[2]); t[7] = (short)f2bf(x1[3]);
    *(bf16x8*)&A_lds[r * 512 + ((s ^ (r & 7)) * 8)] = t;
  }
  __syncthreads();

  const int wv  = tid >> 6;
  const int l   = tid & 63;
  const int l15 = l & 15, lq = l >> 4, l7 = l & 7;
  // wave 2: inn (K=0..255 only), wave 3: hn (K=256..511 only)
  const int ks_lo = (wv == 3) ? 8 : 0;
  const int ks_hi = (wv == 2) ? 8 : 16;

  for (int cs = 0; cs < 4; cs++) {
    f32x4 acc[2][4];
    #pragma unroll
    for (int mf = 0; mf < 2; mf++)
      #pragma unroll
      for (int nf = 0; nf < 4; nf++)
        acc[mf][nf] = (f32x4){0.f, 0.f, 0.f, 0.f};

    for (int ks = ks_lo; ks < ks_hi; ks++) {
      int c = ks * 4 + lq;  // k-chunk 0..63
      bf16x8 b[4];
      #pragma unroll
      for (int nf = 0; nf < 4; nf++) {
        int n = (wv << 8) + cs * 64 + nf * 16 + l15;
        b[nf] = *(const bf16x8*)&Bp6[(((c << 10) + n)) * 8];
      }
      bf16x8 a[2];
      #pragma unroll
      for (int mf = 0; mf < 2; mf++)
        a[mf] = *(const bf16x8*)&A_lds[(mf * 16 + l15) * 512 + ((c ^ l7) * 8)];
      #pragma unroll
      for (int mf = 0; mf < 2; mf++)
        #pragma unroll
        for (int nf = 0; nf < 4; nf++)
          acc[mf][nf] = __builtin_amdgcn_mfma_f32_16x16x32_bf16(
              a[mf], b[nf], acc[mf][nf], 0, 0, 0);
    }

    __syncthreads();  // prev combine reads done before overwriting gate_s
    #pragma unroll
    for (int mf = 0; mf < 2; mf++)
      #pragma unroll
      for (int nf = 0; nf < 4; nf++)
        #pragma unroll
        for (int r = 0; r < 4; r++)
          gate_s[(mf * 16 + lq * 4 + r) * 256 + wv * 64 + nf * 16 + l15] =
              acc[mf][nf][r];
    __syncthreads();

    // combine: 32 rows x 64 cols of this cslice
    #pragma unroll
    for (int i = 0; i < 8; i++) {
      int eid = tid + i * 256;
      int r = eid >> 6;
      int col = eid & 63;
      int g = row0 + r;
      if (g < G_SEG) {
        int c = cs * 64 + col;
        float v0 = gate_s[r * 256 + col];        // ir+hr
        float v1 = gate_s[r * 256 + 64 + col];   // iz+hz
        float v2 = gate_s[r * 256 + 128 + col];  // inn
        float v3 = gate_s[r * 256 + 192 + col];  // hn
        float rr = 1.f / (1.f + expf(-(v0 + b_ih[c] + b_hh[c])));
        float zz = 1.f / (1.f + expf(-(v1 + b_ih[256 + c] + b_hh[256 + c])));
        float nn = tanhf(v2 + b_ih[512 + c] + rr * (v3 + b_hh[512 + c]));
        float sv = s_buf[(size_t)g * H_DIM + c];
        float nh = (1.f - zz) * nn + zz * sv;
        out0[(size_t)g * H_DIM + c] = nh > 0.f ? nh : 0.f;
      }
    }
  }
}

extern "C" void kernel_launch(void* const* d_in, const int* in_sizes, int n_in,
                              void* d_out, int out_size, void* d_ws, size_t ws_size,
                              hipStream_t stream)
{
  (void)in_sizes; (void)n_in; (void)out_size; (void)ws_size;
  const float* node       = (const float*)d_in[0];
  const float* super_node = (const float*)d_in[1];
  const int*   seg        = (const int*)d_in[2];
  const float* w_align    = (const float*)d_in[3];
  const float* b_align    = (const float*)d_in[4];
  const float* w_att      = (const float*)d_in[5];
  const float* b_att      = (const float*)d_in[6];
  const float* w_ih       = (const float*)d_in[7];
  const float* w_hh       = (const float*)d_in[8];
  const float* b_ih       = (const float*)d_in[9];
  const float* b_hh       = (const float*)d_in[10];

  float* out0     = (float*)d_out;                               // G*H
  float* attn_out = (float*)d_out + (size_t)G_SEG * H_DIM;       // N

  float* ws     = (float*)d_ws;
  float* s_buf  = ws;                    //  6,400,000 f32
  float* score  = ws + 6400000;          //    500,000 (dead after k3)
  float* sws    = ws + 6900000;          //     25,000
  float* ctx    = ws + 6925000;          //  6,400,000
  unsigned* m_enc = (unsigned*)(ws + 13325000);  // 25,000
  float* denom  = ws + 13350000;         //     25,000
  ushort* Bp    = (ushort*)score;                 // 65,536 ushort (128KB)
  ushort* Bp6   = (ushort*)(ws + 6500000);        // 524,288 ushort (1MB), still in score region

  hipMemsetAsync(ctx, 0, (size_t)(6400000 + 25000 + 25000) * sizeof(float), stream);

  k1_prep_super<<<G_SEG, 256, 0, stream>>>(super_node, w_align, s_buf, sws);
  k2_score<<<(N_NODES + 3) / 4, 256, 0, stream>>>(node, seg, w_align, b_align, sws, score, m_enc);
  k3_wexp<<<(N_NODES + 255) / 256, 256, 0, stream>>>(score, seg, m_enc, attn_out, denom);
  k4_norm<<<(N_NODES + 255) / 256, 256, 0, stream>>>(seg, denom, attn_out);
  k0_prep_w<<<H_DIM, H_DIM, 0, stream>>>(w_att, Bp);          // after k3: aliases score
  k0b_prep_w6<<<512, 256, 0, stream>>>(w_ih, w_hh, Bp6);      // after k3: aliases score
  k5_hidden_ctx<<<(N_NODES + 127) / 128, 256, 0, stream>>>(node, seg, Bp, b_att, attn_out, ctx);
  k6_mfma<<<(G_SEG + 31) / 32, 256, 0, stream>>>(ctx, s_buf, Bp6, b_ih, b_hh, out0);
}

// Round 4
// 542.917 us; speedup vs baseline: 2.9478x; 1.0785x over previous
//
#include <hip/hip_runtime.h>
#include <math.h>

#define N_NODES 500000
#define G_SEG   25000
#define H_DIM   256

typedef __attribute__((ext_vector_type(4))) float f32x4;
typedef __attribute__((ext_vector_type(8))) short bf16x8;

__device__ __forceinline__ float leaky(float x){ return x > 0.f ? x : 0.01f * x; }

// round-to-nearest-even f32 -> bf16
__device__ __forceinline__ ushort f2bf(float f){
  unsigned u = __float_as_uint(f);
  u += 0x7FFFu + ((u >> 16) & 1u);
  return (ushort)(u >> 16);
}

// order-preserving encode for float atomicMax on unsigned (0 == -inf sentinel:
// all finite floats encode > 0)
__device__ __forceinline__ unsigned enc_f(float f){
  unsigned u = __float_as_uint(f);
  return (u & 0x80000000u) ? ~u : (u | 0x80000000u);
}
__device__ __forceinline__ float dec_f(unsigned u){
  return __uint_as_float((u & 0x80000000u) ? (u ^ 0x80000000u) : ~u);
}

// K0: pre-pack w_attend (256x256 f32) into bf16 fragment layout:
// W[kk][n] -> Bp[((kk>>3)*256 + n)*8 + (kk&7)]
__global__ __launch_bounds__(256) void k0_prep_w(
    const float* __restrict__ w_att, ushort* __restrict__ Bp)
{
  int kk = blockIdx.x, n = threadIdx.x;
  Bp[(((kk >> 3) << 8) + n) * 8 + (kk & 7)] = f2bf(w_att[kk * H_DIM + n]);
}

// K0b: pack GRU weights into Bp6[512 x 1024] bf16 fragment layout.
// Column space n = gate*256 + c:
//  gate0: kk<256 ? w_ih[kk][c]      : w_hh[kk-256][c]       -> ir+hr
//  gate1: kk<256 ? w_ih[kk][256+c]  : w_hh[kk-256][256+c]   -> iz+hz
//  gate2: kk<256 ? w_ih[kk][512+c]  : 0                     -> inn
//  gate3: kk<256 ? 0                : w_hh[kk-256][512+c]   -> hn
__global__ __launch_bounds__(256) void k0b_prep_w6(
    const float* __restrict__ w_ih, const float* __restrict__ w_hh,
    ushort* __restrict__ Bp6)
{
  int kk = blockIdx.x;   // 0..511
  int c  = threadIdx.x;  // 0..255
  #pragma unroll
  for (int gate = 0; gate < 4; gate++) {
    float v;
    if (gate == 0)      v = (kk < 256) ? w_ih[kk * 768 + c]        : w_hh[(kk - 256) * 768 + c];
    else if (gate == 1) v = (kk < 256) ? w_ih[kk * 768 + 256 + c]  : w_hh[(kk - 256) * 768 + 256 + c];
    else if (gate == 2) v = (kk < 256) ? w_ih[kk * 768 + 512 + c]  : 0.f;
    else                v = (kk < 256) ? 0.f                       : w_hh[(kk - 256) * 768 + 512 + c];
    int n = (gate << 8) + c;
    Bp6[(((kk >> 3) << 10) + n) * 8 + (kk & 7)] = f2bf(v);
  }
}

// K1: s = leaky(super_node); sws[g] = dot(s[g], w_align[H:2H]).
// Also zeroes agg row g and (blocks < 196) the m_enc/denom table region.
__global__ __launch_bounds__(256) void k1_prep_super(
    const float* __restrict__ sn, const float* __restrict__ w_align,
    float* __restrict__ s_buf, float* __restrict__ sws,
    float* __restrict__ agg, float* __restrict__ tables /*50k words*/)
{
  int g = blockIdx.x, t = threadIdx.x;
  agg[(size_t)g * H_DIM + t] = 0.f;
  if (g < 196) {
    int idx = g * 256 + t;
    if (idx < 50000) tables[idx] = 0.f;
  }
  float v = sn[g * H_DIM + t];
  float sv = leaky(v);
  s_buf[g * H_DIM + t] = sv;
  float p = sv * w_align[H_DIM + t];
  #pragma unroll
  for (int d = 1; d < 64; d <<= 1) p += __shfl_xor(p, d);
  __shared__ float red[4];
  int wid = t >> 6, lane = t & 63;
  if (lane == 0) red[wid] = p;
  __syncthreads();
  if (t == 0) sws[g] = red[0] + red[1] + red[2] + red[3];
}

// K2: score[i] = leaky(node[i]·wn + sws[seg[i]] + b0); atomicMax segment max.
__global__ __launch_bounds__(256) void k2_score(
    const float* __restrict__ node, const int* __restrict__ seg,
    const float* __restrict__ w_align, const float* __restrict__ b_align,
    const float* __restrict__ sws, float* __restrict__ score,
    unsigned* __restrict__ m_enc)
{
  int wib  = threadIdx.x >> 6;
  int lane = threadIdx.x & 63;
  int row  = blockIdx.x * 4 + wib;
  if (row >= N_NODES) return;
  const float4* n4 = (const float4*)node + row * (H_DIM / 4);
  const float4* w4 = (const float4*)w_align;
  float4 a = n4[lane];
  float4 b = w4[lane];
  float d = a.x * b.x + a.y * b.y + a.z * b.z + a.w * b.w;
  #pragma unroll
  for (int m = 1; m < 64; m <<= 1) d += __shfl_xor(d, m);
  if (lane == 0) {
    int sg = seg[row];
    float sc = leaky(d + sws[sg] + b_align[0]);
    score[row] = sc;
    atomicMax(&m_enc[sg], enc_f(sc));
  }
}

// K3: w = exp(score - m[seg]); segmented-scan + run-leader atomicAdd denom
__global__ __launch_bounds__(256) void k3_wexp(
    const float* __restrict__ score, const int* __restrict__ seg,
    const unsigned* __restrict__ m_enc, float* __restrict__ attn_out,
    float* __restrict__ denom)
{
  int i = blockIdx.x * 256 + threadIdx.x;
  int lane = threadIdx.x & 63;
  float w = 0.f; int sg = -1;
  if (i < N_NODES) {
    sg = seg[i];
    w = expf(score[i] - dec_f(m_enc[sg]));
    attn_out[i] = w;
  }
  float v = w;
  #pragma unroll
  for (int d = 1; d < 64; d <<= 1) {
    float vv = __shfl_up(v, d);
    int   ss = __shfl_up(sg, d);
    if (lane >= d && ss == sg) v += vv;
  }
  int nxt = __shfl_down(sg, 1);
  bool last = (lane == 63) || (nxt != sg);
  if (last && sg >= 0) atomicAdd(&denom[sg], v);
}

// K4: attn /= denom[seg]
__global__ __launch_bounds__(256) void k4_norm(
    const int* __restrict__ seg, const float* __restrict__ denom,
    float* __restrict__ attn_out)
{
  int i = blockIdx.x * 256 + threadIdx.x;
  if (i < N_NODES) attn_out[i] /= denom[seg[i]];
}

// K5a: agg[g] = sum_{i in seg g} attn[i] * node[i]  (pure f32, memory-bound).
// Block = 4 waves x 16 contiguous rows. Lane owns one float4 column slice.
// Run-accumulate while segment unchanged (sorted ids), atomic flush on change.
__global__ __launch_bounds__(256) void k5_agg(
    const float* __restrict__ node, const int* __restrict__ seg,
    const float* __restrict__ attn, float* __restrict__ agg)
{
  const int wib  = threadIdx.x >> 6;
  const int lane = threadIdx.x & 63;
  const int r0 = blockIdx.x * 64 + wib * 16;

  f32x4 run = {0.f, 0.f, 0.f, 0.f};
  int cur = -1;
  #pragma unroll 4
  for (int i = 0; i < 16; i++) {
    int row = r0 + i;
    if (row < N_NODES) {
      int sg = seg[row];
      float av = attn[row];
      f32x4 nv = ((const f32x4*)(node + (size_t)row * H_DIM))[lane];
      if (sg != cur) {
        if (cur >= 0) {
          float* p = &agg[(size_t)cur * H_DIM + lane * 4];
          atomicAdd(p + 0, run[0]); atomicAdd(p + 1, run[1]);
          atomicAdd(p + 2, run[2]); atomicAdd(p + 3, run[3]);
        }
        cur = sg;
        run = av * nv;
      } else {
        run += av * nv;
      }
    }
  }
  if (cur >= 0) {
    float* p = &agg[(size_t)cur * H_DIM + lane * 4];
    atomicAdd(p + 0, run[0]); atomicAdd(p + 1, run[1]);
    atomicAdd(p + 2, run[2]); atomicAdd(p + 3, run[3]);
  }
}

// K5b (MFMA): ctx = agg @ w_attend + b_attend  (G x 256 @ 256 x 256).
// 128-row x 256-col block tile, 4 waves, same fragment scheme as before.
__global__ __launch_bounds__(256, 2) void k5b_ctx(
    const float* __restrict__ agg, const ushort* __restrict__ Bp,
    const float* __restrict__ b_att, float* __restrict__ ctx)
{
  __shared__ __align__(16) ushort A_lds[128 * 256];  // 64KB

  const int tid  = threadIdx.x;
  const int row0 = blockIdx.x * 128;

  #pragma unroll
  for (int i = 0; i < 16; i++) {
    int v = tid + i * 256;
    int r = v >> 5;
    int s = v & 31;
    int grow = row0 + r;
    f32x4 x0 = {0.f, 0.f, 0.f, 0.f}, x1 = {0.f, 0.f, 0.f, 0.f};
    if (grow < G_SEG) {
      const f32x4* p = (const f32x4*)(agg + (size_t)grow * H_DIM) + s * 2;
      x0 = p[0]; x1 = p[1];
    }
    bf16x8 t;
    t[0] = (short)f2bf(x0[0]); t[1] = (short)f2bf(x0[1]);
    t[2] = (short)f2bf(x0[2]); t[3] = (short)f2bf(x0[3]);
    t[4] = (short)f2bf(x1[0]); t[5] = (short)f2bf(x1[1]);
    t[6] = (short)f2bf(x1[2]); t[7] = (short)f2bf(x1[3]);
    *(bf16x8*)&A_lds[r * 256 + ((s ^ (r & 7)) * 8)] = t;
  }
  __syncthreads();

  const int wv  = tid >> 6;
  const int l   = tid & 63;
  const int l15 = l & 15, lq = l >> 4, l7 = l & 7;
  const int colbase = wv * 64 + l15;

  f32x4 acc[8][4];
  #pragma unroll
  for (int mf = 0; mf < 8; mf++)
    #pragma unroll
    for (int nf = 0; nf < 4; nf++)
      acc[mf][nf] = (f32x4){0.f, 0.f, 0.f, 0.f};

  for (int ks = 0; ks < 8; ks++) {
    int c = ks * 4 + lq;
    bf16x8 b[4];
    #pragma unroll
    for (int nf = 0; nf < 4; nf++)
      b[nf] = *(const bf16x8*)&Bp[(((c << 8) + colbase + nf * 16)) * 8];
    bf16x8 a[8];
    #pragma unroll
    for (int mf = 0; mf < 8; mf++)
      a[mf] = *(const bf16x8*)&A_lds[(mf * 16 + l15) * 256 + ((c ^ l7) * 8)];
    #pragma unroll
    for (int mf = 0; mf < 8; mf++)
      #pragma unroll
      for (int nf = 0; nf < 4; nf++)
        acc[mf][nf] = __builtin_amdgcn_mfma_f32_16x16x32_bf16(
            a[mf], b[nf], acc[mf][nf], 0, 0, 0);
  }

  float bias[4];
  #pragma unroll
  for (int nf = 0; nf < 4; nf++) bias[nf] = b_att[colbase + nf * 16];

  #pragma unroll
  for (int mf = 0; mf < 8; mf++) {
    #pragma unroll
    for (int r = 0; r < 4; r++) {
      int grow = row0 + mf * 16 + lq * 4 + r;
      if (grow < G_SEG) {
        #pragma unroll
        for (int nf = 0; nf < 4; nf++)
          ctx[(size_t)grow * H_DIM + colbase + nf * 16] = acc[mf][nf][r] + bias[nf];
      }
    }
  }
}

// K6 (MFMA): GRU gates. A = [elu(ctx) | s] (G x 512) staged bf16 in LDS.
__global__ __launch_bounds__(256, 2) void k6_mfma(
    const float* __restrict__ ctxbuf, const float* __restrict__ s_buf,
    const ushort* __restrict__ Bp6,
    const float* __restrict__ b_ih, const float* __restrict__ b_hh,
    float* __restrict__ out0)
{
  __shared__ __align__(16) ushort A_lds[32 * 512];   // 32KB
  __shared__ __align__(16) float  gate_s[32 * 256];  // 32KB

  const int tid  = threadIdx.x;
  const int row0 = blockIdx.x * 32;

  #pragma unroll
  for (int i = 0; i < 8; i++) {
    int v = tid + i * 256;
    int r = v >> 6;
    int s = v & 63;
    int g = row0 + r;
    f32x4 x0 = {0.f, 0.f, 0.f, 0.f}, x1 = {0.f, 0.f, 0.f, 0.f};
    if (g < G_SEG) {
      const f32x4* p = (s < 32)
          ? (const f32x4*)(ctxbuf + (size_t)g * H_DIM) + s * 2
          : (const f32x4*)(s_buf + (size_t)g * H_DIM) + (s - 32) * 2;
      x0 = p[0]; x1 = p[1];
      if (s < 32) {
        #pragma unroll
        for (int e = 0; e < 4; e++) {
          x0[e] = x0[e] > 0.f ? x0[e] : (expf(x0[e]) - 1.f);
          x1[e] = x1[e] > 0.f ? x1[e] : (expf(x1[e]) - 1.f);
        }
      }
    }
    bf16x8 t;
    t[0] = (short)f2bf(x0[0]); t[1] = (short)f2bf(x0[1]);
    t[2] = (short)f2bf(x0[2]); t[3] = (short)f2bf(x0[3]);
    t[4] = (short)f2bf(x1[0]); t[5] = (short)f2bf(x1[1]);
    t[6] = (short)f2bf(x1[2]); t[7] = (short)f2bf(x1[3]);
    *(bf16x8*)&A_lds[r * 512 + ((s ^ (r & 7)) * 8)] = t;
  }
  __syncthreads();

  const int wv  = tid >> 6;
  const int l   = tid & 63;
  const int l15 = l & 15, lq = l >> 4, l7 = l & 7;
  const int ks_lo = (wv == 3) ? 8 : 0;
  const int ks_hi = (wv == 2) ? 8 : 16;

  for (int cs = 0; cs < 4; cs++) {
    f32x4 acc[2][4];
    #pragma unroll
    for (int mf = 0; mf < 2; mf++)
      #pragma unroll
      for (int nf = 0; nf < 4; nf++)
        acc[mf][nf] = (f32x4){0.f, 0.f, 0.f, 0.f};

    for (int ks = ks_lo; ks < ks_hi; ks++) {
      int c = ks * 4 + lq;
      bf16x8 b[4];
      #pragma unroll
      for (int nf = 0; nf < 4; nf++) {
        int n = (wv << 8) + cs * 64 + nf * 16 + l15;
        b[nf] = *(const bf16x8*)&Bp6[(((c << 10) + n)) * 8];
      }
      bf16x8 a[2];
      #pragma unroll
      for (int mf = 0; mf < 2; mf++)
        a[mf] = *(const bf16x8*)&A_lds[(mf * 16 + l15) * 512 + ((c ^ l7) * 8)];
      #pragma unroll
      for (int mf = 0; mf < 2; mf++)
        #pragma unroll
        for (int nf = 0; nf < 4; nf++)
          acc[mf][nf] = __builtin_amdgcn_mfma_f32_16x16x32_bf16(
              a[mf], b[nf], acc[mf][nf], 0, 0, 0);
    }

    __syncthreads();
    #pragma unroll
    for (int mf = 0; mf < 2; mf++)
      #pragma unroll
      for (int nf = 0; nf < 4; nf++)
        #pragma unroll
        for (int r = 0; r < 4; r++)
          gate_s[(mf * 16 + lq * 4 + r) * 256 + wv * 64 + nf * 16 + l15] =
              acc[mf][nf][r];
    __syncthreads();

    #pragma unroll
    for (int i = 0; i < 8; i++) {
      int eid = tid + i * 256;
      int r = eid >> 6;
      int col = eid & 63;
      int g = row0 + r;
      if (g < G_SEG) {
        int c = cs * 64 + col;
        float v0 = gate_s[r * 256 + col];
        float v1 = gate_s[r * 256 + 64 + col];
        float v2 = gate_s[r * 256 + 128 + col];
        float v3 = gate_s[r * 256 + 192 + col];
        float rr = 1.f / (1.f + expf(-(v0 + b_ih[c] + b_hh[c])));
        float zz = 1.f / (1.f + expf(-(v1 + b_ih[256 + c] + b_hh[256 + c])));
        float nn = tanhf(v2 + b_ih[512 + c] + rr * (v3 + b_hh[512 + c]));
        float sv = s_buf[(size_t)g * H_DIM + c];
        float nh = (1.f - zz) * nn + zz * sv;
        out0[(size_t)g * H_DIM + c] = nh > 0.f ? nh : 0.f;
      }
    }
  }
}

extern "C" void kernel_launch(void* const* d_in, const int* in_sizes, int n_in,
                              void* d_out, int out_size, void* d_ws, size_t ws_size,
                              hipStream_t stream)
{
  (void)in_sizes; (void)n_in; (void)out_size; (void)ws_size;
  const float* node       = (const float*)d_in[0];
  const float* super_node = (const float*)d_in[1];
  const int*   seg        = (const int*)d_in[2];
  const float* w_align    = (const float*)d_in[3];
  const float* b_align    = (const float*)d_in[4];
  const float* w_att      = (const float*)d_in[5];
  const float* b_att      = (const float*)d_in[6];
  const float* w_ih       = (const float*)d_in[7];
  const float* w_hh       = (const float*)d_in[8];
  const float* b_ih       = (const float*)d_in[9];
  const float* b_hh       = (const float*)d_in[10];

  float* out0     = (float*)d_out;                               // G*H
  float* attn_out = (float*)d_out + (size_t)G_SEG * H_DIM;       // N

  float* ws     = (float*)d_ws;
  float* s_buf  = ws;                    //  6,400,000 f32
  float* score  = ws + 6400000;          //    500,000 (dead after k3; packs alias)
  float* sws    = ws + 6900000;          //     25,000
  float* ctx    = ws + 6925000;          //  6,400,000
  unsigned* m_enc = (unsigned*)(ws + 13325000);  // 25,000
  float* denom  = ws + 13350000;         //     25,000
  float* agg    = ws + 13400000;         //  6,400,000 (end: 19.8M f32 = 79.2 MB)
  ushort* Bp    = (ushort*)score;                 // 128KB, aliases dead score
  ushort* Bp6   = (ushort*)(ws + 6500000);        // 1MB, aliases dead score
  float* tables = (float*)m_enc;                  // m_enc + denom, 50k words

  // k1 zeroes agg + m_enc + denom (no hipMemsetAsync — the rocclr fill
  // kernel ran at 86 GB/s and cost ~300 µs/call)
  k1_prep_super<<<G_SEG, 256, 0, stream>>>(super_node, w_align, s_buf, sws, agg, tables);
  k2_score<<<(N_NODES + 3) / 4, 256, 0, stream>>>(node, seg, w_align, b_align, sws, score, m_enc);
  k3_wexp<<<(N_NODES + 255) / 256, 256, 0, stream>>>(score, seg, m_enc, attn_out, denom);
  k4_norm<<<(N_NODES + 255) / 256, 256, 0, stream>>>(seg, denom, attn_out);
  k0_prep_w<<<H_DIM, H_DIM, 0, stream>>>(w_att, Bp);          // after k3: aliases score
  k0b_prep_w6<<<512, 256, 0, stream>>>(w_ih, w_hh, Bp6);      // after k3: aliases score
  k5_agg<<<(N_NODES + 63) / 64, 256, 0, stream>>>(node, seg, attn_out, agg);
  k5b_ctx<<<(G_SEG + 127) / 128, 256, 0, stream>>>(agg, Bp, b_att, ctx);
  k6_mfma<<<(G_SEG + 31) / 32, 256, 0, stream>>>(ctx, s_buf, Bp6, b_ih, b_hh, out0);
}

// Round 5
// 393.947 us; speedup vs baseline: 4.0625x; 1.3781x over previous
//
#include <hip/hip_runtime.h>
#include <math.h>

#define N_NODES 500000
#define G_SEG   25000
#define H_DIM   256
#define SPB     4      // segments per kF block

typedef __attribute__((ext_vector_type(4))) float f32x4;
typedef __attribute__((ext_vector_type(8))) short bf16x8;

__device__ __forceinline__ float leaky(float x){ return x > 0.f ? x : 0.01f * x; }

// round-to-nearest-even f32 -> bf16
__device__ __forceinline__ ushort f2bf(float f){
  unsigned u = __float_as_uint(f);
  u += 0x7FFFu + ((u >> 16) & 1u);
  return (ushort)(u >> 16);
}

// K0: pre-pack w_attend (256x256 f32) into bf16 fragment layout:
// W[kk][n] -> Bp[((kk>>3)*256 + n)*8 + (kk&7)]
__global__ __launch_bounds__(256) void k0_prep_w(
    const float* __restrict__ w_att, ushort* __restrict__ Bp)
{
  int kk = blockIdx.x, n = threadIdx.x;
  Bp[(((kk >> 3) << 8) + n) * 8 + (kk & 7)] = f2bf(w_att[kk * H_DIM + n]);
}

// K0b: pack GRU weights into Bp6[512 x 1024] bf16 fragment layout.
// Column space n = gate*256 + c:
//  gate0: ir+hr  gate1: iz+hz  gate2: inn (K<256 only)  gate3: hn (K>=256 only)
__global__ __launch_bounds__(256) void k0b_prep_w6(
    const float* __restrict__ w_ih, const float* __restrict__ w_hh,
    ushort* __restrict__ Bp6)
{
  int kk = blockIdx.x;   // 0..511
  int c  = threadIdx.x;  // 0..255
  #pragma unroll
  for (int gate = 0; gate < 4; gate++) {
    float v;
    if (gate == 0)      v = (kk < 256) ? w_ih[kk * 768 + c]        : w_hh[(kk - 256) * 768 + c];
    else if (gate == 1) v = (kk < 256) ? w_ih[kk * 768 + 256 + c]  : w_hh[(kk - 256) * 768 + 256 + c];
    else if (gate == 2) v = (kk < 256) ? w_ih[kk * 768 + 512 + c]  : 0.f;
    else                v = (kk < 256) ? 0.f                       : w_hh[(kk - 256) * 768 + 512 + c];
    int n = (gate << 8) + c;
    Bp6[(((kk >> 3) << 10) + n) * 8 + (kk & 7)] = f2bf(v);
  }
}

// K1: s = leaky(super_node); sws[g] = dot(s[g], w_align[H:2H])
__global__ __launch_bounds__(256) void k1_prep_super(
    const float* __restrict__ sn, const float* __restrict__ w_align,
    float* __restrict__ s_buf, float* __restrict__ sws)
{
  int g = blockIdx.x, t = threadIdx.x;
  float v = sn[g * H_DIM + t];
  float sv = leaky(v);
  s_buf[g * H_DIM + t] = sv;
  float p = sv * w_align[H_DIM + t];
  #pragma unroll
  for (int d = 1; d < 64; d <<= 1) p += __shfl_xor(p, d);
  __shared__ float red[4];
  int wid = t >> 6, lane = t & 63;
  if (lane == 0) red[wid] = p;
  __syncthreads();
  if (t == 0) sws[g] = red[0] + red[1] + red[2] + red[3];
}

// KF: fused score + segment softmax + attn-weighted aggregation.
// Sorted segment_ids => each block owns SPB consecutive segments (row ranges
// found by binary search). No global atomics anywhere.
//  phase1 (per seg): wave-per-row dot -> score[r] (global scratch)
//  phase2: wave 0 computes m, d; writes attn[r] = exp(score-m)/d
//  phase3: 256 threads (1 col each) accumulate agg[g][c] = sum attn_r*node[r][c]
//          (node rows re-read L1/L2-hot from phase1), direct store.
__global__ __launch_bounds__(256) void kF_score_softmax_agg(
    const float* __restrict__ node, const int* __restrict__ seg,
    const float* __restrict__ w_align, const float* __restrict__ b_align,
    const float* __restrict__ sws, float* __restrict__ score,
    float* __restrict__ attn_out, float* __restrict__ agg,
    float* __restrict__ bscale)
{
  __shared__ int st_s[SPB + 1];
  const int tid = threadIdx.x;
  const int g0 = blockIdx.x * SPB;

  if (tid <= SPB) {
    int target = g0 + tid;
    int lo = 0, hi = N_NODES;
    while (lo < hi) {           // lower_bound: first i with seg[i] >= target
      int mid = (lo + hi) >> 1;
      if (seg[mid] < target) lo = mid + 1; else hi = mid;
    }
    st_s[tid] = lo;
  }
  __syncthreads();

  const int wv = tid >> 6, lane = tid & 63;
  const float4 wvec = ((const float4*)w_align)[lane];
  const float b0 = b_align[0];

  for (int j = 0; j < SPB; j++) {
    const int g  = g0 + j;
    const int st = st_s[j], en = st_s[j + 1];
    const int cnt = en - st;
    const float swsg = sws[g];

    // phase1: scores (wave per row)
    for (int r = st + wv; r < en; r += 4) {
      float4 a = ((const float4*)node)[(size_t)r * 64 + lane];
      float d = a.x * wvec.x + a.y * wvec.y + a.z * wvec.z + a.w * wvec.w;
      #pragma unroll
      for (int m2 = 1; m2 < 64; m2 <<= 1) d += __shfl_xor(d, m2);
      if (lane == 0) score[r] = leaky(d + swsg + b0);
    }
    __syncthreads();

    // phase2: softmax finalize by wave 0
    if (wv == 0) {
      float m = -3.4e38f;
      for (int r = st + lane; r < en; r += 64) m = fmaxf(m, score[r]);
      #pragma unroll
      for (int d2 = 1; d2 < 64; d2 <<= 1) m = fmaxf(m, __shfl_xor(m, d2));
      float dsum = 0.f;
      for (int r = st + lane; r < en; r += 64) dsum += expf(score[r] - m);
      #pragma unroll
      for (int d2 = 1; d2 < 64; d2 <<= 1) dsum += __shfl_xor(dsum, d2);
      float inv = (cnt > 0) ? 1.f / dsum : 0.f;
      for (int r = st + lane; r < en; r += 64)
        attn_out[r] = expf(score[r] - m) * inv;
      if (lane == 0) bscale[g] = (cnt > 0) ? 1.f : 0.f;
    }
    __syncthreads();

    // phase3: weighted aggregation, one column per thread, rows cache-hot
    float acc = 0.f;
    for (int r = st; r < en; r++)
      acc = fmaf(attn_out[r], node[(size_t)r * H_DIM + tid], acc);
    agg[(size_t)g * H_DIM + tid] = acc;
    // no sync needed: next j touches disjoint rows/segments
  }
}

// K5b (MFMA): ctx = agg @ w_attend + bscale*b_attend  (G x 256 @ 256 x 256).
__global__ __launch_bounds__(256, 2) void k5b_ctx(
    const float* __restrict__ agg, const ushort* __restrict__ Bp,
    const float* __restrict__ b_att, const float* __restrict__ bscale,
    float* __restrict__ ctx)
{
  __shared__ __align__(16) ushort A_lds[128 * 256];  // 64KB

  const int tid  = threadIdx.x;
  const int row0 = blockIdx.x * 128;

  #pragma unroll
  for (int i = 0; i < 16; i++) {
    int v = tid + i * 256;
    int r = v >> 5;
    int s = v & 31;
    int grow = row0 + r;
    f32x4 x0 = {0.f, 0.f, 0.f, 0.f}, x1 = {0.f, 0.f, 0.f, 0.f};
    if (grow < G_SEG) {
      const f32x4* p = (const f32x4*)(agg + (size_t)grow * H_DIM) + s * 2;
      x0 = p[0]; x1 = p[1];
    }
    bf16x8 t;
    t[0] = (short)f2bf(x0[0]); t[1] = (short)f2bf(x0[1]);
    t[2] = (short)f2bf(x0[2]); t[3] = (short)f2bf(x0[3]);
    t[4] = (short)f2bf(x1[0]); t[5] = (short)f2bf(x1[1]);
    t[6] = (short)f2bf(x1[2]); t[7] = (short)f2bf(x1[3]);
    *(bf16x8*)&A_lds[r * 256 + ((s ^ (r & 7)) * 8)] = t;
  }
  __syncthreads();

  const int wv  = tid >> 6;
  const int l   = tid & 63;
  const int l15 = l & 15, lq = l >> 4, l7 = l & 7;
  const int colbase = wv * 64 + l15;

  f32x4 acc[8][4];
  #pragma unroll
  for (int mf = 0; mf < 8; mf++)
    #pragma unroll
    for (int nf = 0; nf < 4; nf++)
      acc[mf][nf] = (f32x4){0.f, 0.f, 0.f, 0.f};

  for (int ks = 0; ks < 8; ks++) {
    int c = ks * 4 + lq;
    bf16x8 b[4];
    #pragma unroll
    for (int nf = 0; nf < 4; nf++)
      b[nf] = *(const bf16x8*)&Bp[(((c << 8) + colbase + nf * 16)) * 8];
    bf16x8 a[8];
    #pragma unroll
    for (int mf = 0; mf < 8; mf++)
      a[mf] = *(const bf16x8*)&A_lds[(mf * 16 + l15) * 256 + ((c ^ l7) * 8)];
    #pragma unroll
    for (int mf = 0; mf < 8; mf++)
      #pragma unroll
      for (int nf = 0; nf < 4; nf++)
        acc[mf][nf] = __builtin_amdgcn_mfma_f32_16x16x32_bf16(
            a[mf], b[nf], acc[mf][nf], 0, 0, 0);
  }

  float bias[4];
  #pragma unroll
  for (int nf = 0; nf < 4; nf++) bias[nf] = b_att[colbase + nf * 16];

  #pragma unroll
  for (int mf = 0; mf < 8; mf++) {
    #pragma unroll
    for (int r = 0; r < 4; r++) {
      int grow = row0 + mf * 16 + lq * 4 + r;
      if (grow < G_SEG) {
        float bsc = bscale[grow];
        #pragma unroll
        for (int nf = 0; nf < 4; nf++)
          ctx[(size_t)grow * H_DIM + colbase + nf * 16] =
              acc[mf][nf][r] + bias[nf] * bsc;
      }
    }
  }
}

// K6 (MFMA): GRU gates. A = [elu(ctx) | s] (G x 512) staged bf16 in LDS.
__global__ __launch_bounds__(256, 2) void k6_mfma(
    const float* __restrict__ ctxbuf, const float* __restrict__ s_buf,
    const ushort* __restrict__ Bp6,
    const float* __restrict__ b_ih, const float* __restrict__ b_hh,
    float* __restrict__ out0)
{
  __shared__ __align__(16) ushort A_lds[32 * 512];   // 32KB
  __shared__ __align__(16) float  gate_s[32 * 256];  // 32KB

  const int tid  = threadIdx.x;
  const int row0 = blockIdx.x * 32;

  #pragma unroll
  for (int i = 0; i < 8; i++) {
    int v = tid + i * 256;
    int r = v >> 6;
    int s = v & 63;
    int g = row0 + r;
    f32x4 x0 = {0.f, 0.f, 0.f, 0.f}, x1 = {0.f, 0.f, 0.f, 0.f};
    if (g < G_SEG) {
      const f32x4* p = (s < 32)
          ? (const f32x4*)(ctxbuf + (size_t)g * H_DIM) + s * 2
          : (const f32x4*)(s_buf + (size_t)g * H_DIM) + (s - 32) * 2;
      x0 = p[0]; x1 = p[1];
      if (s < 32) {
        #pragma unroll
        for (int e = 0; e < 4; e++) {
          x0[e] = x0[e] > 0.f ? x0[e] : (expf(x0[e]) - 1.f);
          x1[e] = x1[e] > 0.f ? x1[e] : (expf(x1[e]) - 1.f);
        }
      }
    }
    bf16x8 t;
    t[0] = (short)f2bf(x0[0]); t[1] = (short)f2bf(x0[1]);
    t[2] = (short)f2bf(x0[2]); t[3] = (short)f2bf(x0[3]);
    t[4] = (short)f2bf(x1[0]); t[5] = (short)f2bf(x1[1]);
    t[6] = (short)f2bf(x1[2]); t[7] = (short)f2bf(x1[3]);
    *(bf16x8*)&A_lds[r * 512 + ((s ^ (r & 7)) * 8)] = t;
  }
  __syncthreads();

  const int wv  = tid >> 6;
  const int l   = tid & 63;
  const int l15 = l & 15, lq = l >> 4, l7 = l & 7;
  const int ks_lo = (wv == 3) ? 8 : 0;
  const int ks_hi = (wv == 2) ? 8 : 16;

  for (int cs = 0; cs < 4; cs++) {
    f32x4 acc[2][4];
    #pragma unroll
    for (int mf = 0; mf < 2; mf++)
      #pragma unroll
      for (int nf = 0; nf < 4; nf++)
        acc[mf][nf] = (f32x4){0.f, 0.f, 0.f, 0.f};

    for (int ks = ks_lo; ks < ks_hi; ks++) {
      int c = ks * 4 + lq;
      bf16x8 b[4];
      #pragma unroll
      for (int nf = 0; nf < 4; nf++) {
        int n = (wv << 8) + cs * 64 + nf * 16 + l15;
        b[nf] = *(const bf16x8*)&Bp6[(((c << 10) + n)) * 8];
      }
      bf16x8 a[2];
      #pragma unroll
      for (int mf = 0; mf < 2; mf++)
        a[mf] = *(const bf16x8*)&A_lds[(mf * 16 + l15) * 512 + ((c ^ l7) * 8)];
      #pragma unroll
      for (int mf = 0; mf < 2; mf++)
        #pragma unroll
        for (int nf = 0; nf < 4; nf++)
          acc[mf][nf] = __builtin_amdgcn_mfma_f32_16x16x32_bf16(
              a[mf], b[nf], acc[mf][nf], 0, 0, 0);
    }

    __syncthreads();
    #pragma unroll
    for (int mf = 0; mf < 2; mf++)
      #pragma unroll
      for (int nf = 0; nf < 4; nf++)
        #pragma unroll
        for (int r = 0; r < 4; r++)
          gate_s[(mf * 16 + lq * 4 + r) * 256 + wv * 64 + nf * 16 + l15] =
              acc[mf][nf][r];
    __syncthreads();

    #pragma unroll
    for (int i = 0; i < 8; i++) {
      int eid = tid + i * 256;
      int r = eid >> 6;
      int col = eid & 63;
      int g = row0 + r;
      if (g < G_SEG) {
        int c = cs * 64 + col;
        float v0 = gate_s[r * 256 + col];
        float v1 = gate_s[r * 256 + 64 + col];
        float v2 = gate_s[r * 256 + 128 + col];
        float v3 = gate_s[r * 256 + 192 + col];
        float rr = 1.f / (1.f + expf(-(v0 + b_ih[c] + b_hh[c])));
        float zz = 1.f / (1.f + expf(-(v1 + b_ih[256 + c] + b_hh[256 + c])));
        float nn = tanhf(v2 + b_ih[512 + c] + rr * (v3 + b_hh[512 + c]));
        float sv = s_buf[(size_t)g * H_DIM + c];
        float nh = (1.f - zz) * nn + zz * sv;
        out0[(size_t)g * H_DIM + c] = nh > 0.f ? nh : 0.f;
      }
    }
  }
}

extern "C" void kernel_launch(void* const* d_in, const int* in_sizes, int n_in,
                              void* d_out, int out_size, void* d_ws, size_t ws_size,
                              hipStream_t stream)
{
  (void)in_sizes; (void)n_in; (void)out_size; (void)ws_size;
  const float* node       = (const float*)d_in[0];
  const float* super_node = (const float*)d_in[1];
  const int*   seg        = (const int*)d_in[2];
  const float* w_align    = (const float*)d_in[3];
  const float* b_align    = (const float*)d_in[4];
  const float* w_att      = (const float*)d_in[5];
  const float* b_att      = (const float*)d_in[6];
  const float* w_ih       = (const float*)d_in[7];
  const float* w_hh       = (const float*)d_in[8];
  const float* b_ih       = (const float*)d_in[9];
  const float* b_hh       = (const float*)d_in[10];

  float* out0     = (float*)d_out;                               // G*H
  float* attn_out = (float*)d_out + (size_t)G_SEG * H_DIM;       // N

  float* ws     = (float*)d_ws;
  float* s_buf  = ws;                          //  6,400,000 f32
  float* score  = ws + 6400000;                //    500,000 (kF scratch, live)
  float* sws    = ws + 6900000;                //     25,000
  float* ctx    = ws + 6925000;                //  6,400,000
  float* agg    = ws + 13400000;               //  6,400,000
  ushort* Bp    = (ushort*)(ws + 19800000);    //  65,536 ushort (128KB)
  ushort* Bp6   = (ushort*)(ws + 19840000);    // 524,288 ushort (1MB)
  float* bscale = ws + 20110000;               //     25,000  (end ~80.5MB)

  // no memsets anywhere: kF writes agg/bscale densely, direct stores only
  k0_prep_w<<<H_DIM, H_DIM, 0, stream>>>(w_att, Bp);
  k0b_prep_w6<<<512, 256, 0, stream>>>(w_ih, w_hh, Bp6);
  k1_prep_super<<<G_SEG, 256, 0, stream>>>(super_node, w_align, s_buf, sws);
  kF_score_softmax_agg<<<G_SEG / SPB, 256, 0, stream>>>(
      node, seg, w_align, b_align, sws, score, attn_out, agg, bscale);
  k5b_ctx<<<(G_SEG + 127) / 128, 256, 0, stream>>>(agg, Bp, b_att, bscale, ctx);
  k6_mfma<<<(G_SEG + 31) / 32, 256, 0, stream>>>(ctx, s_buf, Bp6, b_ih, b_hh, out0);
}

// Round 6
// 289.139 us; speedup vs baseline: 5.5351x; 1.3625x over previous
//
#include <hip/hip_runtime.h>
#include <math.h>

#define N_NODES 500000
#define G_SEG   25000
#define H_DIM   256
#define SPB     4      // segments per kF block

typedef __attribute__((ext_vector_type(4))) float f32x4;
typedef __attribute__((ext_vector_type(8))) short bf16x8;

__device__ __forceinline__ float leaky(float x){ return x > 0.f ? x : 0.01f * x; }

// round-to-nearest-even f32 -> bf16
__device__ __forceinline__ ushort f2bf(float f){
  unsigned u = __float_as_uint(f);
  u += 0x7FFFu + ((u >> 16) & 1u);
  return (ushort)(u >> 16);
}

// K_starts: starts[g] = first row index with seg >= g (sorted seg). starts[G]=N.
__global__ __launch_bounds__(256) void k_starts(
    const int* __restrict__ seg, int* __restrict__ starts)
{
  int i = blockIdx.x * 256 + threadIdx.x;
  if (i >= N_NODES) return;
  int s = seg[i];
  int prev = (i == 0) ? -1 : seg[i - 1];
  for (int g = prev + 1; g <= s; g++) starts[g] = i;
  if (i == N_NODES - 1)
    for (int g = s + 1; g <= G_SEG; g++) starts[g] = N_NODES;
}

// K0: pre-pack w_attend (256x256 f32) into bf16 fragment layout:
// W[kk][n] -> Bp[((kk>>3)*256 + n)*8 + (kk&7)]
__global__ __launch_bounds__(256) void k0_prep_w(
    const float* __restrict__ w_att, ushort* __restrict__ Bp)
{
  int kk = blockIdx.x, n = threadIdx.x;
  Bp[(((kk >> 3) << 8) + n) * 8 + (kk & 7)] = f2bf(w_att[kk * H_DIM + n]);
}

// K0b: pack GRU weights into Bp6[512 x 1024] bf16 fragment layout.
// Column space n = gate*256 + c:
//  gate0: ir+hr  gate1: iz+hz  gate2: inn (K<256 only)  gate3: hn (K>=256 only)
__global__ __launch_bounds__(256) void k0b_prep_w6(
    const float* __restrict__ w_ih, const float* __restrict__ w_hh,
    ushort* __restrict__ Bp6)
{
  int kk = blockIdx.x;   // 0..511
  int c  = threadIdx.x;  // 0..255
  #pragma unroll
  for (int gate = 0; gate < 4; gate++) {
    float v;
    if (gate == 0)      v = (kk < 256) ? w_ih[kk * 768 + c]        : w_hh[(kk - 256) * 768 + c];
    else if (gate == 1) v = (kk < 256) ? w_ih[kk * 768 + 256 + c]  : w_hh[(kk - 256) * 768 + 256 + c];
    else if (gate == 2) v = (kk < 256) ? w_ih[kk * 768 + 512 + c]  : 0.f;
    else                v = (kk < 256) ? 0.f                       : w_hh[(kk - 256) * 768 + 512 + c];
    int n = (gate << 8) + c;
    Bp6[(((kk >> 3) << 10) + n) * 8 + (kk & 7)] = f2bf(v);
  }
}

// K1: s = leaky(super_node); sws[g] = dot(s[g], w_align[H:2H])
__global__ __launch_bounds__(256) void k1_prep_super(
    const float* __restrict__ sn, const float* __restrict__ w_align,
    float* __restrict__ s_buf, float* __restrict__ sws)
{
  int g = blockIdx.x, t = threadIdx.x;
  float v = sn[g * H_DIM + t];
  float sv = leaky(v);
  s_buf[g * H_DIM + t] = sv;
  float p = sv * w_align[H_DIM + t];
  #pragma unroll
  for (int d = 1; d < 64; d <<= 1) p += __shfl_xor(p, d);
  __shared__ float red[4];
  int wid = t >> 6, lane = t & 63;
  if (lane == 0) red[wid] = p;
  __syncthreads();
  if (t == 0) sws[g] = red[0] + red[1] + red[2] + red[3];
}

// KF: fused score + segment softmax + weighted aggregation, ONE pass over node.
// Wave-per-row dot (all lanes get the reduced score via shfl_xor); each wave
// keeps an online-softmax running state (m, sum, pacc[4 cols/lane]) over its
// rows. Cross-wave combine per segment via 4KB LDS. attn finalized by a cheap
// re-read of the score scratch (L1/L2-hot). No atomics, no binary search.
__global__ __launch_bounds__(256) void kF_score_softmax_agg(
    const float* __restrict__ node, const int* __restrict__ starts,
    const float* __restrict__ w_align, const float* __restrict__ b_align,
    const float* __restrict__ sws, float* __restrict__ score,
    float* __restrict__ attn_out, float* __restrict__ agg,
    float* __restrict__ bscale)
{
  __shared__ float cpart[4][H_DIM];  // per-wave partial agg (4KB)
  __shared__ float wm[4], wsum[4];
  __shared__ int st_s[SPB + 1];

  const int tid = threadIdx.x;
  const int g0 = blockIdx.x * SPB;
  if (tid <= SPB) st_s[tid] = starts[g0 + tid];
  __syncthreads();

  const int wv = tid >> 6, lane = tid & 63;
  const float4 wvec = ((const float4*)w_align)[lane];
  const float b0 = b_align[0];

  for (int j = 0; j < SPB; j++) {
    const int g = g0 + j;
    const int st = st_s[j], en = st_s[j + 1];
    const float swsg = sws[g];

    float m = -3.4e38f, sum = 0.f;
    f32x4 pacc = {0.f, 0.f, 0.f, 0.f};

    for (int r = st + wv; r < en; r += 4) {
      f32x4 a = ((const f32x4*)node)[(size_t)r * 64 + lane];
      float d = a[0] * wvec.x + a[1] * wvec.y + a[2] * wvec.z + a[3] * wvec.w;
      #pragma unroll
      for (int m2 = 1; m2 < 64; m2 <<= 1) d += __shfl_xor(d, m2);
      float sc = leaky(d + swsg + b0);
      if (lane == 0) score[r] = sc;
      if (sc <= m) {                       // wave-uniform branch
        float p = __expf(sc - m);
        sum += p;
        pacc += p * a;
      } else {
        float scale = __expf(m - sc);      // m=-3.4e38 first time -> 0
        sum = sum * scale + 1.f;
        pacc = pacc * scale + a;
        m = sc;
      }
    }

    if (j > 0) __syncthreads();            // protect cpart reuse
    ((f32x4*)&cpart[wv][0])[lane] = pacc;
    if (lane == 0) { wm[wv] = m; wsum[wv] = sum; }
    __syncthreads();

    // all threads redundantly reduce the 4 wave scalars
    float m0 = fmaxf(fmaxf(wm[0], wm[1]), fmaxf(wm[2], wm[3]));
    float f0 = (wm[0] > -1e38f) ? __expf(wm[0] - m0) : 0.f;
    float f1 = (wm[1] > -1e38f) ? __expf(wm[1] - m0) : 0.f;
    float f2 = (wm[2] > -1e38f) ? __expf(wm[2] - m0) : 0.f;
    float f3 = (wm[3] > -1e38f) ? __expf(wm[3] - m0) : 0.f;
    float D = wsum[0] * f0 + wsum[1] * f1 + wsum[2] * f2 + wsum[3] * f3;
    float invD = (D > 0.f) ? 1.f / D : 0.f;

    float v = cpart[0][tid] * f0 + cpart[1][tid] * f1 +
              cpart[2][tid] * f2 + cpart[3][tid] * f3;
    agg[(size_t)g * H_DIM + tid] = v * invD;
    if (tid == 0) bscale[g] = (D > 0.f) ? 1.f : 0.f;

    // attn finalize: score is block-hot
    for (int r = st + tid; r < en; r += 256)
      attn_out[r] = __expf(score[r] - m0) * invD;
  }
}

// K5b (MFMA): ctx = agg @ w_attend + bscale*b_attend  (G x 256 @ 256 x 256).
__global__ __launch_bounds__(256, 2) void k5b_ctx(
    const float* __restrict__ agg, const ushort* __restrict__ Bp,
    const float* __restrict__ b_att, const float* __restrict__ bscale,
    float* __restrict__ ctx)
{
  __shared__ __align__(16) ushort A_lds[128 * 256];  // 64KB

  const int tid  = threadIdx.x;
  const int row0 = blockIdx.x * 128;

  #pragma unroll
  for (int i = 0; i < 16; i++) {
    int v = tid + i * 256;
    int r = v >> 5;
    int s = v & 31;
    int grow = row0 + r;
    f32x4 x0 = {0.f, 0.f, 0.f, 0.f}, x1 = {0.f, 0.f, 0.f, 0.f};
    if (grow < G_SEG) {
      const f32x4* p = (const f32x4*)(agg + (size_t)grow * H_DIM) + s * 2;
      x0 = p[0]; x1 = p[1];
    }
    bf16x8 t;
    t[0] = (short)f2bf(x0[0]); t[1] = (short)f2bf(x0[1]);
    t[2] = (short)f2bf(x0[2]); t[3] = (short)f2bf(x0[3]);
    t[4] = (short)f2bf(x1[0]); t[5] = (short)f2bf(x1[1]);
    t[6] = (short)f2bf(x1[2]); t[7] = (short)f2bf(x1[3]);
    *(bf16x8*)&A_lds[r * 256 + ((s ^ (r & 7)) * 8)] = t;
  }
  __syncthreads();

  const int wv  = tid >> 6;
  const int l   = tid & 63;
  const int l15 = l & 15, lq = l >> 4, l7 = l & 7;
  const int colbase = wv * 64 + l15;

  f32x4 acc[8][4];
  #pragma unroll
  for (int mf = 0; mf < 8; mf++)
    #pragma unroll
    for (int nf = 0; nf < 4; nf++)
      acc[mf][nf] = (f32x4){0.f, 0.f, 0.f, 0.f};

  for (int ks = 0; ks < 8; ks++) {
    int c = ks * 4 + lq;
    bf16x8 b[4];
    #pragma unroll
    for (int nf = 0; nf < 4; nf++)
      b[nf] = *(const bf16x8*)&Bp[(((c << 8) + colbase + nf * 16)) * 8];
    bf16x8 a[8];
    #pragma unroll
    for (int mf = 0; mf < 8; mf++)
      a[mf] = *(const bf16x8*)&A_lds[(mf * 16 + l15) * 256 + ((c ^ l7) * 8)];
    #pragma unroll
    for (int mf = 0; mf < 8; mf++)
      #pragma unroll
      for (int nf = 0; nf < 4; nf++)
        acc[mf][nf] = __builtin_amdgcn_mfma_f32_16x16x32_bf16(
            a[mf], b[nf], acc[mf][nf], 0, 0, 0);
  }

  float bias[4];
  #pragma unroll
  for (int nf = 0; nf < 4; nf++) bias[nf] = b_att[colbase + nf * 16];

  #pragma unroll
  for (int mf = 0; mf < 8; mf++) {
    #pragma unroll
    for (int r = 0; r < 4; r++) {
      int grow = row0 + mf * 16 + lq * 4 + r;
      if (grow < G_SEG) {
        float bsc = bscale[grow];
        #pragma unroll
        for (int nf = 0; nf < 4; nf++)
          ctx[(size_t)grow * H_DIM + colbase + nf * 16] =
              acc[mf][nf][r] + bias[nf] * bsc;
      }
    }
  }
}

// K6 (MFMA) v2: wave owns a 64-col slice for ALL 4 gates (acc[4][2][4],
// statically indexed) -> no gate_s LDS, single barrier, balanced waves.
// Block: 256 thr = 4 waves, 32 rows, A = [elu(ctx)|s] bf16 in LDS (32KB).
__global__ __launch_bounds__(256, 2) void k6_mfma(
    const float* __restrict__ ctxbuf, const float* __restrict__ s_buf,
    const ushort* __restrict__ Bp6,
    const float* __restrict__ b_ih, const float* __restrict__ b_hh,
    float* __restrict__ out0)
{
  __shared__ __align__(16) ushort A_lds[32 * 512];   // 32KB

  const int tid  = threadIdx.x;
  const int row0 = blockIdx.x * 32;

  #pragma unroll
  for (int i = 0; i < 8; i++) {
    int v = tid + i * 256;
    int r = v >> 6;
    int s = v & 63;
    int g = row0 + r;
    f32x4 x0 = {0.f, 0.f, 0.f, 0.f}, x1 = {0.f, 0.f, 0.f, 0.f};
    if (g < G_SEG) {
      const f32x4* p = (s < 32)
          ? (const f32x4*)(ctxbuf + (size_t)g * H_DIM) + s * 2
          : (const f32x4*)(s_buf + (size_t)g * H_DIM) + (s - 32) * 2;
      x0 = p[0]; x1 = p[1];
      if (s < 32) {
        #pragma unroll
        for (int e = 0; e < 4; e++) {
          x0[e] = x0[e] > 0.f ? x0[e] : (__expf(x0[e]) - 1.f);
          x1[e] = x1[e] > 0.f ? x1[e] : (__expf(x1[e]) - 1.f);
        }
      }
    }
    bf16x8 t;
    t[0] = (short)f2bf(x0[0]); t[1] = (short)f2bf(x0[1]);
    t[2] = (short)f2bf(x0[2]); t[3] = (short)f2bf(x0[3]);
    t[4] = (short)f2bf(x1[0]); t[5] = (short)f2bf(x1[1]);
    t[6] = (short)f2bf(x1[2]); t[7] = (short)f2bf(x1[3]);
    *(bf16x8*)&A_lds[r * 512 + ((s ^ (r & 7)) * 8)] = t;
  }
  __syncthreads();

  const int wv  = tid >> 6;
  const int l   = tid & 63;
  const int l15 = l & 15, lq = l >> 4, l7 = l & 7;

  f32x4 acc[4][2][4];  // [gate][mf][nf]
  #pragma unroll
  for (int gt = 0; gt < 4; gt++)
    #pragma unroll
    for (int mf = 0; mf < 2; mf++)
      #pragma unroll
      for (int nf = 0; nf < 4; nf++)
        acc[gt][mf][nf] = (f32x4){0.f, 0.f, 0.f, 0.f};

  for (int ks = 0; ks < 16; ks++) {
    int c = ks * 4 + lq;  // k-chunk 0..63
    bf16x8 a[2];
    #pragma unroll
    for (int mf = 0; mf < 2; mf++)
      a[mf] = *(const bf16x8*)&A_lds[(mf * 16 + l15) * 512 + ((c ^ l7) * 8)];
    #pragma unroll
    for (int gt = 0; gt < 4; gt++) {
      if (gt == 2 && ks >= 8) continue;  // inn: K<256 only
      if (gt == 3 && ks < 8) continue;   // hn:  K>=256 only
      #pragma unroll
      for (int nf = 0; nf < 4; nf++) {
        int n = (gt << 8) + (wv << 6) + nf * 16 + l15;
        bf16x8 b = *(const bf16x8*)&Bp6[(((c << 10) + n)) * 8];
        acc[gt][0][nf] = __builtin_amdgcn_mfma_f32_16x16x32_bf16(
            a[0], b, acc[gt][0][nf], 0, 0, 0);
        acc[gt][1][nf] = __builtin_amdgcn_mfma_f32_16x16x32_bf16(
            a[1], b, acc[gt][1][nf], 0, 0, 0);
      }
    }
  }

  // epilogue fully in-register
  #pragma unroll
  for (int nf = 0; nf < 4; nf++) {
    int cc = (wv << 6) + nf * 16 + l15;
    float bir = b_ih[cc] + b_hh[cc];
    float biz = b_ih[256 + cc] + b_hh[256 + cc];
    float bin_ = b_ih[512 + cc];
    float bhn  = b_hh[512 + cc];
    #pragma unroll
    for (int mf = 0; mf < 2; mf++) {
      #pragma unroll
      for (int rr = 0; rr < 4; rr++) {
        int grow = row0 + mf * 16 + lq * 4 + rr;
        if (grow < G_SEG) {
          float v0 = acc[0][mf][nf][rr];
          float v1 = acc[1][mf][nf][rr];
          float v2 = acc[2][mf][nf][rr];
          float v3 = acc[3][mf][nf][rr];
          float r_ = 1.f / (1.f + __expf(-(v0 + bir)));
          float z_ = 1.f / (1.f + __expf(-(v1 + biz)));
          float n_ = tanhf(v2 + bin_ + r_ * (v3 + bhn));
          float sv = s_buf[(size_t)grow * H_DIM + cc];
          float nh = (1.f - z_) * n_ + z_ * sv;
          out0[(size_t)grow * H_DIM + cc] = nh > 0.f ? nh : 0.f;
        }
      }
    }
  }
}

extern "C" void kernel_launch(void* const* d_in, const int* in_sizes, int n_in,
                              void* d_out, int out_size, void* d_ws, size_t ws_size,
                              hipStream_t stream)
{
  (void)in_sizes; (void)n_in; (void)out_size; (void)ws_size;
  const float* node       = (const float*)d_in[0];
  const float* super_node = (const float*)d_in[1];
  const int*   seg        = (const int*)d_in[2];
  const float* w_align    = (const float*)d_in[3];
  const float* b_align    = (const float*)d_in[4];
  const float* w_att      = (const float*)d_in[5];
  const float* b_att      = (const float*)d_in[6];
  const float* w_ih       = (const float*)d_in[7];
  const float* w_hh       = (const float*)d_in[8];
  const float* b_ih       = (const float*)d_in[9];
  const float* b_hh       = (const float*)d_in[10];

  float* out0     = (float*)d_out;                               // G*H
  float* attn_out = (float*)d_out + (size_t)G_SEG * H_DIM;       // N

  float* ws     = (float*)d_ws;
  float* s_buf  = ws;                          //  6,400,000 f32
  float* score  = ws + 6400000;                //    500,000 (kF scratch)
  float* sws    = ws + 6900000;                //     25,000
  float* ctx    = ws + 6925000;                //  6,400,000
  float* agg    = ws + 13325000;               //  6,400,000
  ushort* Bp    = (ushort*)(ws + 19725000);    //  65,536 ushort (128KB)
  ushort* Bp6   = (ushort*)(ws + 19760000);    // 524,288 ushort (1MB)
  float* bscale = ws + 20025000;               //     25,000
  int*   starts = (int*)(ws + 20050000);       //     25,001 int (end ~80.3MB)

  k_starts<<<(N_NODES + 255) / 256, 256, 0, stream>>>(seg, starts);
  k0_prep_w<<<H_DIM, H_DIM, 0, stream>>>(w_att, Bp);
  k0b_prep_w6<<<512, 256, 0, stream>>>(w_ih, w_hh, Bp6);
  k1_prep_super<<<G_SEG, 256, 0, stream>>>(super_node, w_align, s_buf, sws);
  kF_score_softmax_agg<<<G_SEG / SPB, 256, 0, stream>>>(
      node, starts, w_align, b_align, sws, score, attn_out, agg, bscale);
  k5b_ctx<<<(G_SEG + 127) / 128, 256, 0, stream>>>(agg, Bp, b_att, bscale, ctx);
  k6_mfma<<<(G_SEG + 31) / 32, 256, 0, stream>>>(ctx, s_buf, Bp6, b_ih, b_hh, out0);
}